// Round 3
// baseline (2247.485 us; speedup 1.0000x reference)
//
#include <hip/hip_runtime.h>
#include <hip/hip_bf16.h>

typedef __hip_bfloat16 bf16;

#define B_   2
#define C_   128
#define T_   32
#define N_   512
#define K_   16
#define HID_ 512
#define TN   (T_*N_)          // 16384
#define PTS  (B_*T_*N_)       // 32768

__device__ __forceinline__ float b2f(bf16 v){ return __bfloat162float(v); }
__device__ __forceinline__ bf16  f2b(float v){ return __float2bfloat16(v); }

// ---------- dtype detector: f32 data viewed as bf16 has garbage halves ----------
// True bf16 N(0,1) data: every 16-bit word is a sane bf16 (|v| < 8, exp < 0x84).
// True f32 data: even-indexed 16-bit words are float32 low-mantissa bits ->
// ~46% have exponent field >= 0x89. Count over the first 2048 halves of x.
__global__ __launch_bounds__(256) void detect_kernel(const void* __restrict__ x,
                                                     int* __restrict__ flag)
{
  __shared__ int cnt;
  if (threadIdx.x == 0) cnt = 0;
  __syncthreads();
  const unsigned short* u = (const unsigned short*)x;
  int w = 0;
#pragma unroll
  for (int j = 0; j < 8; ++j) {
    unsigned short v = u[threadIdx.x*8 + j];
    int e = (v >> 7) & 0xFF;
    if (e >= 0x89) w++;
  }
  if (w) atomicAdd(&cnt, w);
  __syncthreads();
  if (threadIdx.x == 0) *flag = (cnt > 32) ? 1 : 0;   // 1 = float32 inputs
}

// ---------- convert all inputs to f32 workspace copies ----------
__device__ __forceinline__ float ldc(const void* p, int i, bool f32) {
  return f32 ? ((const float*)p)[i] : b2f(((const bf16*)p)[i]);
}

__global__ __launch_bounds__(256) void convert_kernel(
    const void* x, const void* wq, const void* wk, const void* wv,
    const void* w1, const void* w2, const void* g, const void* bb,
    const void* m, const void* v, const int* __restrict__ flag,
    float* __restrict__ xf, float* __restrict__ wqf, float* __restrict__ wkf,
    float* __restrict__ wvf, float* __restrict__ w1f, float* __restrict__ w2f,
    float* __restrict__ gf, float* __restrict__ bf_, float* __restrict__ mf,
    float* __restrict__ vf)
{
  bool f32 = (*flag != 0);
  int i = blockIdx.x*256 + threadIdx.x;            // grid covers 4,375,040 exactly
  if (i < 4194304) { xf[i]  = ldc(x, i, f32); return; }  i -= 4194304;
  if (i < 16384)   { wqf[i] = ldc(wq, i, f32); return; } i -= 16384;
  if (i < 16384)   { wkf[i] = ldc(wk, i, f32); return; } i -= 16384;
  if (i < 16384)   { wvf[i] = ldc(wv, i, f32); return; } i -= 16384;
  if (i < 65536)   { w1f[i] = ldc(w1, i, f32); return; } i -= 65536;
  if (i < 65536)   { w2f[i] = ldc(w2, i, f32); return; } i -= 65536;
  if (i < 128)     { gf[i]  = ldc(g, i, f32); return; }  i -= 128;
  if (i < 128)     { bf_[i] = ldc(bb, i, f32); return; } i -= 128;
  if (i < 128)     { mf[i]  = ldc(m, i, f32); return; }  i -= 128;
  if (i < 128)     { vf[i]  = ldc(v, i, f32); return; }
}

// ---------- QKV projections + point-major transpose of x ----------
__device__ __forceinline__ void proj_one(const float* __restrict__ W,
                                         const float (*xs)[C_+1],
                                         int lane, int wave, float* dst)
{
  for (int pass = 0; pass < 2; ++pass) {
    int o0 = pass*64 + wave*16;                    // wave-uniform -> scalar W loads
    float acc[16];
#pragma unroll
    for (int j=0;j<16;++j) acc[j]=0.f;
    for (int c=0;c<C_;++c) {
      float xv = xs[lane][c];
#pragma unroll
      for (int j=0;j<16;++j)
        acc[j] = fmaf(W[(o0+j)*C_ + c], xv, acc[j]);
    }
#pragma unroll
    for (int j=0;j<16;++j) dst[o0+j] = acc[j];
  }
}

__global__ __launch_bounds__(256) void proj_kernel(
    const float* __restrict__ xf,
    const float* __restrict__ wqf, const float* __restrict__ wkf, const float* __restrict__ wvf,
    float* __restrict__ xT, float* QT /* later aliased as hT */,
    float* __restrict__ KT, float* __restrict__ VT)
{
  __shared__ float xs[64][C_+1];                   // 33.0 KB, odd stride (2-way free)
  int tid = threadIdx.x;
  int p0  = blockIdx.x * 64;
  int b   = p0 >> 14; int tn = p0 & (TN-1);
  const float* xbase = xf + (size_t)b*C_*TN + tn;
  for (int i = tid; i < 64*C_; i += 256) {
    int c = i >> 6, p = i & 63;                    // coalesced over n
    xs[p][c] = xbase[(size_t)c*TN + p];
  }
  __syncthreads();
  for (int i = tid; i < 64*C_; i += 256) {
    int p = i >> 7, c = i & 127;                   // coalesced over c
    xT[(size_t)(p0+p)*C_ + c] = xs[p][c];
  }
  int lane = tid & 63;
  int wave = tid >> 6;
  proj_one(wqf, xs, lane, wave, QT + (size_t)(p0+lane)*C_);
  proj_one(wkf, xs, lane, wave, KT + (size_t)(p0+lane)*C_);
  proj_one(wvf, xs, lane, wave, VT + (size_t)(p0+lane)*C_);
}

// ---------- top-K=16 nearest neighbors over 3N pooled candidates ----------
__global__ __launch_bounds__(128) void knn_kernel(const float* __restrict__ xf,
                                                  int* __restrict__ idxout)
{
  __shared__ float cand[3][3*N_];                  // 18 KB
  int blk = blockIdx.x;
  int nc = blk & 3, t = (blk>>2)&31, b = blk>>7;
  int tid = threadIdx.x;
  for (int i = tid; i < 3*3*N_; i += 128) {
    int ch = i / (3*N_); int m = i - ch*(3*N_);
    int j = m >> 9, nn = m & (N_-1);
    int tt = t - 1 + j; tt = tt < 0 ? 0 : (tt > T_-1 ? T_-1 : tt);
    cand[ch][m] = xf[((size_t)(b*C_+ch)*T_ + tt)*N_ + nn];
  }
  __syncthreads();
  int n = nc*128 + tid;
  float a0 = cand[0][N_+n], a1 = cand[1][N_+n], a2 = cand[2][N_+n];
  float bd[16]; int bi[16];
#pragma unroll
  for (int j=0;j<16;++j){ bd[j]=3.0e38f; bi[j]=0; }
  for (int m=0;m<3*N_;++m) {
    float dx = a0 - cand[0][m];
    float dy = a1 - cand[1][m];
    float dz = a2 - cand[2][m];
    // exact numpy order, no fma contraction: (dx*dx + dy*dy) + dz*dz
    float d2 = __fadd_rn(__fadd_rn(__fmul_rn(dx,dx), __fmul_rn(dy,dy)), __fmul_rn(dz,dz));
    if (d2 < bd[15]) {                             // strict < : lowest-index-first ties
#pragma unroll
      for (int s=15;s>=0;--s) {
        bool cp = (s>0) && (d2 < bd[s-1]);
        bool cs = (d2 < bd[s]);
        float nd = cp ? bd[s-1] : (cs ? d2 : bd[s]);
        int   ni = cp ? bi[s-1] : (cs ? m  : bi[s]);
        bd[s]=nd; bi[s]=ni;
      }
    }
  }
  int point = (b*T_ + t)*N_ + n;
#pragma unroll
  for (int j=0;j<16;++j) idxout[point*K_ + j] = bi[j];
}

// ---------- attention (gather form) + residual + BN -> hT (aliases QT) ----------
__global__ __launch_bounds__(256) void attn_kernel(
    const int* __restrict__ idxin, const float* __restrict__ xT,
    float* qhT /* in: QT, out: hT */, const float* __restrict__ KT,
    const float* __restrict__ VT,
    const float* __restrict__ gf, const float* __restrict__ bf_,
    const float* __restrict__ mf, const float* __restrict__ vf)
{
  __shared__ int   col_lds[2][16];
  __shared__ float qbuf[2][C_];
  __shared__ float kbuf[2][K_][C_+1];
  __shared__ float e_lds[2][4][16];
  int tid = threadIdx.x;
  int pt = tid >> 7, o = tid & 127;
  int point = blockIdx.x*2 + pt;
  int b = point >> 14; int tn = point & (TN-1); int t = tn >> 9;
  if (o < K_) {
    int m = idxin[point*K_ + o];
    int j = m >> 9, nn = m & (N_-1);
    int tt = t-1+j; tt = tt<0?0:(tt>T_-1?T_-1:tt);
    col_lds[pt][o] = ((b*T_ + tt)*N_ + nn)*C_;
  }
  int self = point*C_;
  qbuf[pt][o] = qhT[self + o];                     // QT reads done before first sync
  __syncthreads();
  for (int i = tid; i < 2*K_*C_; i += 256) {       // gather 16 K-columns (512B each)
    int pp = i >> 11, rem = i & 2047, k = rem >> 7, oo = rem & 127;
    kbuf[pp][k][oo] = KT[col_lds[pp][k] + oo];
  }
  __syncthreads();
  if (tid < 128) {                                 // one thread per (point, head, k)
    int pp = tid >> 6, j = tid & 63, hd = j >> 4, k = j & 15;
    const float* qp = &qbuf[pp][hd*32];
    const float* kp = &kbuf[pp][k][hd*32];
    float e = 0.f;
#pragma unroll
    for (int d=0; d<32; ++d) e = fmaf(qp[d], kp[d], e);
    // energy = q.(Kself - Knb)/sqrt(D); self term is k-constant -> dropped
    e_lds[pp][hd][k] = -e * 0.17677669529663687f;
  }
  __syncthreads();
  int hd = o >> 5;
  float e[16]; float mx = -3e38f;
#pragma unroll
  for (int k=0;k<K_;++k){ e[k]=e_lds[pt][hd][k]; mx=fmaxf(mx,e[k]); }
  float ssum=0.f;
#pragma unroll
  for (int k=0;k<K_;++k){ e[k]=__expf(e[k]-mx); ssum+=e[k]; }
  float inv = 1.f/ssum;
  float acc = VT[self + o];                        // agg = Vself - sum attn*Vnb
  for (int k=0;k<K_;++k)
    acc = fmaf(-(e[k]*inv), VT[col_lds[pt][k] + o], acc);
  float hv = xT[self + o] + acc;
  float sc = gf[o] / sqrtf(vf[o] + 1e-5f);
  qhT[self + o] = (hv - mf[o])*sc + bf_[o];
}

// ---------- fused MLP (f32, halved-hid LDS) -> out channels 4..131 ----------
__global__ __launch_bounds__(256) void mlp_kernel(const float* __restrict__ hT,
                                                  const float* __restrict__ w1f,
                                                  const float* __restrict__ w2f,
                                                  const int* __restrict__ flag,
                                                  void* out)
{
  __shared__ float hs[64][C_+1];                   // 33.0 KB
  __shared__ float hid[64][261];                   // 66.8 KB (half of HID at a time)
  int tid = threadIdx.x;
  int p0 = blockIdx.x*64;
  int lane = tid & 63, wave = tid >> 6;
  for (int i=tid; i<64*C_; i+=256) {
    int p = i>>7, c = i&127;
    hs[p][c] = hT[(size_t)(p0+p)*C_ + c];
  }
  __syncthreads();
  float acc[2][16];
#pragma unroll
  for (int a=0;a<2;++a)
#pragma unroll
    for (int j=0;j<16;++j) acc[a][j]=0.f;
  for (int half=0; half<2; ++half) {
    // stage 1: hidden units [half*256, half*256+256)
    for (int pass=0; pass<4; ++pass) {
      int u0 = pass*64 + wave*16;                  // [0,256)
      int ug = half*256 + u0;
      float a1[16];
#pragma unroll
      for (int j=0;j<16;++j) a1[j]=0.f;
      for (int c=0;c<C_;++c) {
        float hv = hs[lane][c];
#pragma unroll
        for (int j=0;j<16;++j) a1[j] = fmaf(w1f[(ug+j)*C_+c], hv, a1[j]);
      }
#pragma unroll
      for (int j=0;j<16;++j) {
        float z = a1[j];
        hid[lane][u0+j] = z > 0.f ? z : 0.2f*z;
      }
    }
    __syncthreads();
    // stage 2 partial: accumulate over this half's 256 hidden units
    for (int opass=0; opass<2; ++opass) {
      int o0 = opass*64 + wave*16;
      for (int u=0; u<256; ++u) {
        float hv = hid[lane][u];
#pragma unroll
        for (int j=0;j<16;++j)
          acc[opass][j] = fmaf(w2f[(o0+j)*HID_ + half*256 + u], hv, acc[opass][j]);
      }
    }
    __syncthreads();                               // before next half overwrites hid
  }
  int point = p0 + lane;
  int b = point >> 14; int tn = point & (TN-1);
  size_t obase = (size_t)b*132*TN + tn;
  bool f32 = (*flag != 0);
#pragma unroll
  for (int opass=0;opass<2;++opass) {
    int o0 = opass*64 + wave*16;
#pragma unroll
    for (int j=0;j<16;++j) {
      size_t oi = obase + (size_t)(4+o0+j)*TN;
      if (f32) ((float*)out)[oi] = acc[opass][j];
      else     ((bf16*)out)[oi] = f2b(acc[opass][j]);
    }
  }
}

// ---------- passthrough channels 0..3 ----------
__global__ __launch_bounds__(256) void copy_kernel(const float* __restrict__ xf,
                                                   const int* __restrict__ flag,
                                                   void* out)
{
  int i = blockIdx.x*256 + threadIdx.x;            // exactly B*4*TN = 131072
  int b = i >> 16;                                 // 4*TN = 65536
  int r = i & 65535;
  float v = xf[(size_t)b*C_*TN + r];
  size_t oi = (size_t)b*132*TN + r;
  if (*flag) ((float*)out)[oi] = v;                // bit-exact (xf is a bit copy)
  else       ((bf16*)out)[oi] = f2b(v);            // exact bf16 round-trip
}

extern "C" void kernel_launch(void* const* d_in, const int* in_sizes, int n_in,
                              void* d_out, int out_size, void* d_ws, size_t ws_size,
                              hipStream_t stream)
{
  (void)in_sizes; (void)n_in; (void)out_size; (void)ws_size;
  char* ws = (char*)d_ws;
  const size_t MB = (size_t)1<<20;
  float* xf  = (float*)(ws + 0*MB);      // 16 MB
  float* QT  = (float*)(ws + 16*MB);     // 16 MB (becomes hT after attn)
  float* KT  = (float*)(ws + 32*MB);     // 16 MB
  float* VT  = (float*)(ws + 48*MB);     // 16 MB
  float* xT  = (float*)(ws + 64*MB);     // 16 MB
  int*   idxw= (int*  )(ws + 80*MB);     // 2 MB
  float* wqf = (float*)(ws + 82*MB);             // 64 KB
  float* wkf = (float*)(ws + 82*MB + 0x10000);   // 64 KB
  float* wvf = (float*)(ws + 82*MB + 0x20000);   // 64 KB
  float* w1f = (float*)(ws + 82*MB + 0x30000);   // 256 KB
  float* w2f = (float*)(ws + 82*MB + 0x70000);   // 256 KB
  float* gf  = (float*)(ws + 82*MB + 0xB0000);
  float* bf_ = (float*)(ws + 82*MB + 0xB0200);
  float* mf  = (float*)(ws + 82*MB + 0xB0400);
  float* vf  = (float*)(ws + 82*MB + 0xB0600);
  int*  flag = (int*  )(ws + 82*MB + 0xB0800);

  detect_kernel <<<dim3(1), dim3(256), 0, stream>>>(d_in[0], flag);
  convert_kernel<<<dim3(17090), dim3(256), 0, stream>>>(
      d_in[0], d_in[1], d_in[2], d_in[3], d_in[4], d_in[5],
      d_in[6], d_in[7], d_in[8], d_in[9], flag,
      xf, wqf, wkf, wvf, w1f, w2f, gf, bf_, mf, vf);
  proj_kernel <<<dim3(PTS/64), dim3(256), 0, stream>>>(xf, wqf, wkf, wvf, xT, QT, KT, VT);
  knn_kernel  <<<dim3(B_*T_*(N_/128)), dim3(128), 0, stream>>>(xf, idxw);
  attn_kernel <<<dim3(PTS/2), dim3(256), 0, stream>>>(idxw, xT, QT /*->hT*/, KT, VT, gf, bf_, mf, vf);
  mlp_kernel  <<<dim3(PTS/64), dim3(256), 0, stream>>>(QT /*hT*/, w1f, w2f, flag, d_out);
  copy_kernel <<<dim3(B_*4*TN/256), dim3(256), 0, stream>>>(xf, flag, d_out);
}

// Round 4
// 968.864 us; speedup vs baseline: 2.3197x; 2.3197x over previous
//
#include <hip/hip_runtime.h>
#include <hip/hip_bf16.h>

typedef __hip_bfloat16 bf16;
typedef __attribute__((ext_vector_type(8))) short short8;   // 8 bf16 = MFMA A/B frag
typedef __attribute__((ext_vector_type(4))) float f32x4;    // MFMA C/D frag

#define B_   2
#define C_   128
#define T_   32
#define N_   512
#define K_   16
#define HID_ 512
#define TN   (T_*N_)          // 16384
#define PTS  (B_*T_*N_)       // 32768

#define MFMA_BF16(a,b,c) __builtin_amdgcn_mfma_f32_16x16x32_bf16((a),(b),(c),0,0,0)

__device__ __forceinline__ float b2f(bf16 v){ return __bfloat162float(v); }
__device__ __forceinline__ bf16  f2b(float v){ return __float2bfloat16(v); }

// ---------- dtype detector: f32 data viewed as bf16 has garbage halves ----------
__global__ __launch_bounds__(256) void detect_kernel(const void* __restrict__ x,
                                                     int* __restrict__ flag)
{
  __shared__ int cnt;
  if (threadIdx.x == 0) cnt = 0;
  __syncthreads();
  const unsigned short* u = (const unsigned short*)x;
  int w = 0;
#pragma unroll
  for (int j = 0; j < 8; ++j) {
    unsigned short v = u[threadIdx.x*8 + j];
    int e = (v >> 7) & 0xFF;
    if (e >= 0x89) w++;
  }
  if (w) atomicAdd(&cnt, w);
  __syncthreads();
  if (threadIdx.x == 0) *flag = (cnt > 32) ? 1 : 0;   // 1 = float32 inputs
}

__device__ __forceinline__ float ldc(const void* p, int i, bool f32) {
  return f32 ? ((const float*)p)[i] : b2f(((const bf16*)p)[i]);
}

// ---------- convert: x -> f32 copy; weights -> bf16 copies; bn -> f32 ----------
__global__ __launch_bounds__(256) void convert_kernel(
    const void* x, const void* wq, const void* wk, const void* wv,
    const void* w1, const void* w2, const void* g, const void* bb,
    const void* m, const void* v, const int* __restrict__ flag,
    float* __restrict__ xf, bf16* __restrict__ wqb, bf16* __restrict__ wkb,
    bf16* __restrict__ wvb, bf16* __restrict__ w1b, bf16* __restrict__ w2b,
    float* __restrict__ gf, float* __restrict__ bf_, float* __restrict__ mf,
    float* __restrict__ vf)
{
  bool f32 = (*flag != 0);
  int i = blockIdx.x*256 + threadIdx.x;            // grid covers 4,375,040 exactly
  if (i < 4194304) { xf[i]  = ldc(x, i, f32); return; }       i -= 4194304;
  if (i < 16384)   { wqb[i] = f2b(ldc(wq, i, f32)); return; } i -= 16384;
  if (i < 16384)   { wkb[i] = f2b(ldc(wk, i, f32)); return; } i -= 16384;
  if (i < 16384)   { wvb[i] = f2b(ldc(wv, i, f32)); return; } i -= 16384;
  if (i < 65536)   { w1b[i] = f2b(ldc(w1, i, f32)); return; } i -= 65536;
  if (i < 65536)   { w2b[i] = f2b(ldc(w2, i, f32)); return; } i -= 65536;
  if (i < 128)     { gf[i]  = ldc(g, i, f32); return; }       i -= 128;
  if (i < 128)     { bf_[i] = ldc(bb, i, f32); return; }      i -= 128;
  if (i < 128)     { mf[i]  = ldc(m, i, f32); return; }       i -= 128;
  if (i < 128)     { vf[i]  = ldc(v, i, f32); return; }
}

// ---------- MFMA GEMM helper for C=128-K projections: D[p][o] += A[p][c]*W[o][c] ----------
__device__ __forceinline__ void proj_gemm(const bf16* __restrict__ W,
                                          bf16 (*ys)[136],
                                          const short8 am[4][4],
                                          int mrow, int quad, int wave)
{
#pragma unroll
  for (int oi = 0; oi < 2; ++oi) {
    int ot = wave*2 + oi;
    f32x4 acc[4];
#pragma unroll
    for (int mt=0;mt<4;++mt) acc[mt] = (f32x4){0.f,0.f,0.f,0.f};
#pragma unroll
    for (int kq=0;kq<4;++kq) {
      short8 bfr = *(const short8*)&W[(ot*16+mrow)*C_ + kq*32 + quad*8];
#pragma unroll
      for (int mt=0;mt<4;++mt) acc[mt] = MFMA_BF16(am[mt][kq], bfr, acc[mt]);
    }
#pragma unroll
    for (int mt=0;mt<4;++mt)
#pragma unroll
      for (int r=0;r<4;++r)
        ys[mt*16 + quad*4 + r][ot*16 + mrow] = f2b(acc[mt][r]);
  }
}

__device__ __forceinline__ void tile_store128(bf16* __restrict__ dst /* + p0*C_ */,
                                              const bf16 (*ys)[136], int tid)
{
#pragma unroll
  for (int it=0; it<4; ++it) {
    int flat = (it*256 + tid)*8;
    int p = flat >> 7, c = flat & 127;
    *(short8*)&dst[(size_t)p*C_ + c] = *(const short8*)&ys[p][c];
  }
}

// ---------- QKV projections (MFMA) + point-major bf16 copy of x ----------
__global__ __launch_bounds__(256) void proj_kernel(
    const float* __restrict__ xf,
    const bf16* __restrict__ wqb, const bf16* __restrict__ wkb, const bf16* __restrict__ wvb,
    bf16* __restrict__ xTb, bf16* QT, bf16* __restrict__ KT, bf16* __restrict__ VT)
{
  __shared__ bf16 xs[64][136];                     // A-tile [point][c], 17.4 KB
  __shared__ bf16 ys[64][136];                     // D-tile staging, 17.4 KB
  int tid = threadIdx.x;
  int p0  = blockIdx.x * 64;
  int b   = p0 >> 14; int tn0 = p0 & (TN-1);
  const float* xbase = xf + (size_t)b*C_*TN + tn0;
#pragma unroll
  for (int it=0; it<32; ++it) {                    // transpose-load, coalesced over n
    int i = it*256 + tid;
    int c = i >> 6, p = i & 63;
    xs[p][c] = f2b(xbase[(size_t)c*TN + p]);
  }
  __syncthreads();
  tile_store128(xTb + (size_t)p0*C_, xs, tid);     // point-major bf16 x
  int lane = tid & 63, wave = tid >> 6;
  int mrow = lane & 15, quad = lane >> 4;
  short8 am[4][4];                                 // A-frags for all 64 points
#pragma unroll
  for (int mt=0;mt<4;++mt)
#pragma unroll
    for (int kq=0;kq<4;++kq)
      am[mt][kq] = *(const short8*)&xs[mt*16 + mrow][kq*32 + quad*8];

  proj_gemm(wqb, ys, am, mrow, quad, wave);
  __syncthreads();
  tile_store128(QT + (size_t)p0*C_, ys, tid);
  __syncthreads();
  proj_gemm(wkb, ys, am, mrow, quad, wave);
  __syncthreads();
  tile_store128(KT + (size_t)p0*C_, ys, tid);
  __syncthreads();
  proj_gemm(wvb, ys, am, mrow, quad, wave);
  __syncthreads();
  tile_store128(VT + (size_t)p0*C_, ys, tid);
}

// ---------- top-K=16 nearest neighbors over 3N pooled candidates ----------
__global__ __launch_bounds__(128) void knn_kernel(const float* __restrict__ xf,
                                                  int* __restrict__ idxout)
{
  __shared__ float cand[3][3*N_];                  // 18 KB
  int blk = blockIdx.x;
  int nc = blk & 3, t = (blk>>2)&31, b = blk>>7;
  int tid = threadIdx.x;
  for (int i = tid; i < 3*3*N_; i += 128) {
    int ch = i / (3*N_); int m = i - ch*(3*N_);
    int j = m >> 9, nn = m & (N_-1);
    int tt = t - 1 + j; tt = tt < 0 ? 0 : (tt > T_-1 ? T_-1 : tt);
    cand[ch][m] = xf[((size_t)(b*C_+ch)*T_ + tt)*N_ + nn];
  }
  __syncthreads();
  int n = nc*128 + tid;
  float a0 = cand[0][N_+n], a1 = cand[1][N_+n], a2 = cand[2][N_+n];
  float bd[16]; int bi[16];
#pragma unroll
  for (int j=0;j<16;++j){ bd[j]=3.0e38f; bi[j]=0; }
  for (int m=0;m<3*N_;++m) {
    float dx = a0 - cand[0][m];
    float dy = a1 - cand[1][m];
    float dz = a2 - cand[2][m];
    float d2 = __fadd_rn(__fadd_rn(__fmul_rn(dx,dx), __fmul_rn(dy,dy)), __fmul_rn(dz,dz));
    if (d2 < bd[15]) {                             // strict < : lowest-index-first ties
#pragma unroll
      for (int s=15;s>=0;--s) {
        bool cp = (s>0) && (d2 < bd[s-1]);
        bool cs = (d2 < bd[s]);
        float nd = cp ? bd[s-1] : (cs ? d2 : bd[s]);
        int   ni = cp ? bi[s-1] : (cs ? m  : bi[s]);
        bd[s]=nd; bi[s]=ni;
      }
    }
  }
  int point = (b*T_ + t)*N_ + n;
#pragma unroll
  for (int j=0;j<16;++j) idxout[point*K_ + j] = bi[j];
}

// ---------- attention (gather form, bf16) + residual + BN -> hT (aliases QT) ----------
__global__ __launch_bounds__(256) void attn_kernel(
    const int* __restrict__ idxin, const bf16* __restrict__ xTb,
    bf16* qhT /* in: QT, out: hT */, const bf16* __restrict__ KT,
    const bf16* __restrict__ VT,
    const float* __restrict__ gf, const float* __restrict__ bf_,
    const float* __restrict__ mf, const float* __restrict__ vf)
{
  __shared__ int   col_lds[2][16];
  __shared__ float qbuf[2][C_];
  __shared__ bf16  kbuf[2][K_][C_+4];
  __shared__ float e_lds[2][4][16];
  int tid = threadIdx.x;
  int pt = tid >> 7, o = tid & 127;
  int point = blockIdx.x*2 + pt;
  int b = point >> 14; int tn = point & (TN-1); int t = tn >> 9;
  if (o < K_) {
    int m = idxin[point*K_ + o];
    int j = m >> 9, nn = m & (N_-1);
    int tt = t-1+j; tt = tt<0?0:(tt>T_-1?T_-1:tt);
    col_lds[pt][o] = ((b*T_ + tt)*N_ + nn)*C_;
  }
  int self = point*C_;
  qbuf[pt][o] = b2f(qhT[self + o]);                // QT reads done before first sync
  __syncthreads();
  for (int i = tid; i < 2*K_*C_; i += 256) {       // gather 16 K-columns (256B each)
    int pp = i >> 11, rem = i & 2047, k = rem >> 7, oo = rem & 127;
    kbuf[pp][k][oo] = KT[col_lds[pp][k] + oo];
  }
  __syncthreads();
  if (tid < 128) {                                 // one thread per (point, head, k)
    int pp = tid >> 6, j = tid & 63, hd = j >> 4, k = j & 15;
    const float* qp = &qbuf[pp][hd*32];
    const bf16*  kp = &kbuf[pp][k][hd*32];
    float e = 0.f;
#pragma unroll
    for (int d=0; d<32; ++d) e = fmaf(qp[d], b2f(kp[d]), e);
    // energy = q.(Kself - Knb)/sqrt(D); self term is k-constant -> dropped
    e_lds[pp][hd][k] = -e * 0.17677669529663687f;
  }
  __syncthreads();
  int hd = o >> 5;
  float e[16]; float mx = -3e38f;
#pragma unroll
  for (int k=0;k<K_;++k){ e[k]=e_lds[pt][hd][k]; mx=fmaxf(mx,e[k]); }
  float ssum=0.f;
#pragma unroll
  for (int k=0;k<K_;++k){ e[k]=__expf(e[k]-mx); ssum+=e[k]; }
  float inv = 1.f/ssum;
  float acc = b2f(VT[self + o]);                   // agg = Vself - sum attn*Vnb
  for (int k=0;k<K_;++k)
    acc = fmaf(-(e[k]*inv), b2f(VT[col_lds[pt][k] + o]), acc);
  float hv = b2f(xTb[self + o]) + acc;
  float sc = gf[o] / sqrtf(vf[o] + 1e-5f);
  qhT[self + o] = f2b((hv - mf[o])*sc + bf_[o]);   // hT role
}

// ---------- fused MLP via MFMA: y = W2 . leaky_relu(W1 . h) -> out ch 4..131 ----------
__global__ __launch_bounds__(256) void mlp_kernel(const bf16* __restrict__ hT,
                                                  const bf16* __restrict__ w1b,
                                                  const bf16* __restrict__ w2b,
                                                  const int* __restrict__ flag,
                                                  void* out)
{
  __shared__ bf16  hs[64][136];                    // 17.4 KB
  __shared__ bf16  hid[64][520];                   // 66.6 KB
  __shared__ float yf[64][133];                    // 34.0 KB  (total 118 KB)
  int tid = threadIdx.x;
  int p0 = blockIdx.x*64;
  int lane = tid & 63, wave = tid >> 6;
  int mrow = lane & 15, quad = lane >> 4;
#pragma unroll
  for (int it=0; it<4; ++it) {                     // coalesced 16B loads of hT tile
    int flat = (it*256 + tid)*8;
    int p = flat >> 7, c = flat & 127;
    *(short8*)&hs[p][c] = *(const short8*)&hT[(size_t)(p0+p)*C_ + c];
  }
  __syncthreads();
  // ---- stage 1: hid = leaky_relu(H x W1^T); wave w owns otiles 8w..8w+7 ----
  {
    short8 am[4][4];
#pragma unroll
    for (int mt=0;mt<4;++mt)
#pragma unroll
      for (int kq=0;kq<4;++kq)
        am[mt][kq] = *(const short8*)&hs[mt*16 + mrow][kq*32 + quad*8];
    for (int ot = wave*8; ot < wave*8 + 8; ++ot) {
      f32x4 acc[4];
#pragma unroll
      for (int mt=0;mt<4;++mt) acc[mt] = (f32x4){0.f,0.f,0.f,0.f};
#pragma unroll
      for (int kq=0;kq<4;++kq) {
        short8 bfr = *(const short8*)&w1b[(ot*16+mrow)*C_ + kq*32 + quad*8];
#pragma unroll
        for (int mt=0;mt<4;++mt) acc[mt] = MFMA_BF16(am[mt][kq], bfr, acc[mt]);
      }
#pragma unroll
      for (int mt=0;mt<4;++mt)
#pragma unroll
        for (int r=0;r<4;++r) {
          float z = acc[mt][r];
          hid[mt*16 + quad*4 + r][ot*16 + mrow] = f2b(z > 0.f ? z : 0.2f*z);
        }
    }
  }
  __syncthreads();
  // ---- stage 2: Y = hid x W2^T; wave w owns points 16w..16w+15, all 128 outputs ----
  {
    short8 ha[16];
#pragma unroll
    for (int ks=0;ks<16;++ks)
      ha[ks] = *(const short8*)&hid[wave*16 + mrow][ks*32 + quad*8];
#pragma unroll
    for (int otp=0; otp<4; ++otp) {                // 2 independent acc chains
      f32x4 acc0 = (f32x4){0.f,0.f,0.f,0.f};
      f32x4 acc1 = (f32x4){0.f,0.f,0.f,0.f};
#pragma unroll
      for (int ks=0;ks<16;++ks) {
        short8 b0 = *(const short8*)&w2b[((otp*2  )*16+mrow)*HID_ + ks*32 + quad*8];
        short8 b1 = *(const short8*)&w2b[((otp*2+1)*16+mrow)*HID_ + ks*32 + quad*8];
        acc0 = MFMA_BF16(ha[ks], b0, acc0);
        acc1 = MFMA_BF16(ha[ks], b1, acc1);
      }
#pragma unroll
      for (int r=0;r<4;++r) {
        yf[wave*16 + quad*4 + r][(otp*2  )*16 + mrow] = acc0[r];
        yf[wave*16 + quad*4 + r][(otp*2+1)*16 + mrow] = acc1[r];
      }
    }
  }
  __syncthreads();
  // ---- coalesced store (f32 or bf16 out per flag) ----
  bool f32o = (*flag != 0);
  int p = tid & 63;
  int point = p0 + p;
  int b = point >> 14, tn = point & (TN-1);
  size_t obase = (size_t)b*132*TN + tn;
#pragma unroll
  for (int j = 0; j < 32; ++j) {
    int o = (tid >> 6)*32 + j;
    float vv = yf[p][o];
    size_t oi = obase + (size_t)(4+o)*TN;
    if (f32o) ((float*)out)[oi] = vv;
    else      ((bf16*)out)[oi] = f2b(vv);
  }
}

// ---------- passthrough channels 0..3 ----------
__global__ __launch_bounds__(256) void copy_kernel(const float* __restrict__ xf,
                                                   const int* __restrict__ flag,
                                                   void* out)
{
  int i = blockIdx.x*256 + threadIdx.x;            // exactly B*4*TN = 131072
  int b = i >> 16;                                 // 4*TN = 65536
  int r = i & 65535;
  float v = xf[(size_t)b*C_*TN + r];
  size_t oi = (size_t)b*132*TN + r;
  if (*flag) ((float*)out)[oi] = v;                // bit-exact
  else       ((bf16*)out)[oi] = f2b(v);            // exact round-trip
}

extern "C" void kernel_launch(void* const* d_in, const int* in_sizes, int n_in,
                              void* d_out, int out_size, void* d_ws, size_t ws_size,
                              hipStream_t stream)
{
  (void)in_sizes; (void)n_in; (void)out_size; (void)ws_size;
  char* ws = (char*)d_ws;
  const size_t MB = (size_t)1<<20;
  float* xf  = (float*)(ws + 0*MB);      // 16 MB
  bf16*  QT  = (bf16* )(ws + 16*MB);     // 8 MB (becomes hT after attn)
  bf16*  KT  = (bf16* )(ws + 24*MB);     // 8 MB
  bf16*  VT  = (bf16* )(ws + 32*MB);     // 8 MB
  bf16*  xTb = (bf16* )(ws + 40*MB);     // 8 MB
  int*   idxw= (int*  )(ws + 48*MB);     // 2 MB
  bf16*  wqb = (bf16* )(ws + 50*MB);             // 32 KB
  bf16*  wkb = (bf16* )(ws + 50*MB + 0x8000);    // 32 KB
  bf16*  wvb = (bf16* )(ws + 50*MB + 0x10000);   // 32 KB
  bf16*  w1b = (bf16* )(ws + 50*MB + 0x18000);   // 128 KB
  bf16*  w2b = (bf16* )(ws + 50*MB + 0x38000);   // 128 KB
  float* gf  = (float*)(ws + 50*MB + 0x58000);
  float* bf_ = (float*)(ws + 50*MB + 0x58200);
  float* mf  = (float*)(ws + 50*MB + 0x58400);
  float* vf  = (float*)(ws + 50*MB + 0x58600);
  int*  flag = (int*  )(ws + 50*MB + 0x58800);

  detect_kernel <<<dim3(1), dim3(256), 0, stream>>>(d_in[0], flag);
  convert_kernel<<<dim3(17090), dim3(256), 0, stream>>>(
      d_in[0], d_in[1], d_in[2], d_in[3], d_in[4], d_in[5],
      d_in[6], d_in[7], d_in[8], d_in[9], flag,
      xf, wqb, wkb, wvb, w1b, w2b, gf, bf_, mf, vf);
  proj_kernel <<<dim3(PTS/64), dim3(256), 0, stream>>>(xf, wqb, wkb, wvb, xTb, QT, KT, VT);
  knn_kernel  <<<dim3(B_*T_*(N_/128)), dim3(128), 0, stream>>>(xf, idxw);
  attn_kernel <<<dim3(PTS/2), dim3(256), 0, stream>>>(idxw, xTb, QT /*->hT*/, KT, VT, gf, bf_, mf, vf);
  mlp_kernel  <<<dim3(PTS/64), dim3(256), 0, stream>>>(QT /*hT*/, w1b, w2b, flag, d_out);
  copy_kernel <<<dim3(B_*4*TN/256), dim3(256), 0, stream>>>(xf, flag, d_out);
}

// Round 5
// 339.751 us; speedup vs baseline: 6.6151x; 2.8517x over previous
//
#include <hip/hip_runtime.h>
#include <hip/hip_bf16.h>

typedef __hip_bfloat16 bf16;
typedef __attribute__((ext_vector_type(8))) short short8;   // 8 bf16 = MFMA A/B frag
typedef __attribute__((ext_vector_type(4))) float f32x4;    // MFMA C/D frag

#define B_   2
#define C_   128
#define T_   32
#define N_   512
#define K_   16
#define HID_ 512
#define TN   (T_*N_)          // 16384
#define PTS  (B_*T_*N_)       // 32768

#define MFMA_BF16(a,b,c) __builtin_amdgcn_mfma_f32_16x16x32_bf16((a),(b),(c),0,0,0)

__device__ __forceinline__ float b2f(bf16 v){ return __bfloat162float(v); }
__device__ __forceinline__ bf16  f2b(float v){ return __float2bfloat16(v); }

// ---------- dtype detector: f32 data viewed as bf16 has garbage halves ----------
__global__ __launch_bounds__(256) void detect_kernel(const void* __restrict__ x,
                                                     int* __restrict__ flag)
{
  __shared__ int cnt;
  if (threadIdx.x == 0) cnt = 0;
  __syncthreads();
  const unsigned short* u = (const unsigned short*)x;
  int w = 0;
#pragma unroll
  for (int j = 0; j < 8; ++j) {
    unsigned short v = u[threadIdx.x*8 + j];
    int e = (v >> 7) & 0xFF;
    if (e >= 0x89) w++;
  }
  if (w) atomicAdd(&cnt, w);
  __syncthreads();
  if (threadIdx.x == 0) *flag = (cnt > 32) ? 1 : 0;   // 1 = float32 inputs
}

__device__ __forceinline__ float ldc(const void* p, int i, bool f32) {
  return f32 ? ((const float*)p)[i] : b2f(((const bf16*)p)[i]);
}

// ---------- convert: x -> f32 copy; weights -> bf16 copies; bn -> f32 ----------
__global__ __launch_bounds__(256) void convert_kernel(
    const void* x, const void* wq, const void* wk, const void* wv,
    const void* w1, const void* w2, const void* g, const void* bb,
    const void* m, const void* v, const int* __restrict__ flag,
    float* __restrict__ xf, bf16* __restrict__ wqb, bf16* __restrict__ wkb,
    bf16* __restrict__ wvb, bf16* __restrict__ w1b, bf16* __restrict__ w2b,
    float* __restrict__ gf, float* __restrict__ bf_, float* __restrict__ mf,
    float* __restrict__ vf)
{
  bool f32 = (*flag != 0);
  int i = blockIdx.x*256 + threadIdx.x;            // grid covers 4,375,040 exactly
  if (i < 4194304) { xf[i]  = ldc(x, i, f32); return; }       i -= 4194304;
  if (i < 16384)   { wqb[i] = f2b(ldc(wq, i, f32)); return; } i -= 16384;
  if (i < 16384)   { wkb[i] = f2b(ldc(wk, i, f32)); return; } i -= 16384;
  if (i < 16384)   { wvb[i] = f2b(ldc(wv, i, f32)); return; } i -= 16384;
  if (i < 65536)   { w1b[i] = f2b(ldc(w1, i, f32)); return; } i -= 65536;
  if (i < 65536)   { w2b[i] = f2b(ldc(w2, i, f32)); return; } i -= 65536;
  if (i < 128)     { gf[i]  = ldc(g, i, f32); return; }       i -= 128;
  if (i < 128)     { bf_[i] = ldc(bb, i, f32); return; }      i -= 128;
  if (i < 128)     { mf[i]  = ldc(m, i, f32); return; }       i -= 128;
  if (i < 128)     { vf[i]  = ldc(v, i, f32); return; }
}

// ---------- MFMA GEMM helper for C=128-K projections: D[p][o] += A[p][c]*W[o][c] ----------
__device__ __forceinline__ void proj_gemm(const bf16* __restrict__ W,
                                          bf16 (*ys)[136],
                                          const short8 am[4][4],
                                          int mrow, int quad, int wave)
{
#pragma unroll
  for (int oi = 0; oi < 2; ++oi) {
    int ot = wave*2 + oi;
    f32x4 acc[4];
#pragma unroll
    for (int mt=0;mt<4;++mt) acc[mt] = (f32x4){0.f,0.f,0.f,0.f};
#pragma unroll
    for (int kq=0;kq<4;++kq) {
      short8 bfr = *(const short8*)&W[(ot*16+mrow)*C_ + kq*32 + quad*8];
#pragma unroll
      for (int mt=0;mt<4;++mt) acc[mt] = MFMA_BF16(am[mt][kq], bfr, acc[mt]);
    }
#pragma unroll
    for (int mt=0;mt<4;++mt)
#pragma unroll
      for (int r=0;r<4;++r)
        ys[mt*16 + quad*4 + r][ot*16 + mrow] = f2b(acc[mt][r]);
  }
}

__device__ __forceinline__ void tile_store128(bf16* __restrict__ dst /* + p0*C_ */,
                                              const bf16 (*ys)[136], int tid)
{
#pragma unroll
  for (int it=0; it<4; ++it) {
    int flat = (it*256 + tid)*8;
    int p = flat >> 7, c = flat & 127;
    *(short8*)&dst[(size_t)p*C_ + c] = *(const short8*)&ys[p][c];
  }
}

// ---------- QKV projections (MFMA) + point-major bf16 copy of x ----------
__global__ __launch_bounds__(256) void proj_kernel(
    const float* __restrict__ xf,
    const bf16* __restrict__ wqb, const bf16* __restrict__ wkb, const bf16* __restrict__ wvb,
    bf16* __restrict__ xTb, bf16* QT, bf16* __restrict__ KT, bf16* __restrict__ VT)
{
  __shared__ bf16 xs[64][136];                     // A-tile [point][c], 17.4 KB
  __shared__ bf16 ys[64][136];                     // D-tile staging, 17.4 KB
  int tid = threadIdx.x;
  int p0  = blockIdx.x * 64;
  int b   = p0 >> 14; int tn0 = p0 & (TN-1);
  const float* xbase = xf + (size_t)b*C_*TN + tn0;
#pragma unroll
  for (int it=0; it<32; ++it) {                    // transpose-load, coalesced over n
    int i = it*256 + tid;
    int c = i >> 6, p = i & 63;
    xs[p][c] = f2b(xbase[(size_t)c*TN + p]);
  }
  __syncthreads();
  tile_store128(xTb + (size_t)p0*C_, xs, tid);     // point-major bf16 x
  int lane = tid & 63, wave = tid >> 6;
  int mrow = lane & 15, quad = lane >> 4;
  short8 am[4][4];                                 // A-frags for all 64 points
#pragma unroll
  for (int mt=0;mt<4;++mt)
#pragma unroll
    for (int kq=0;kq<4;++kq)
      am[mt][kq] = *(const short8*)&xs[mt*16 + mrow][kq*32 + quad*8];

  proj_gemm(wqb, ys, am, mrow, quad, wave);
  __syncthreads();
  tile_store128(QT + (size_t)p0*C_, ys, tid);
  __syncthreads();
  proj_gemm(wkb, ys, am, mrow, quad, wave);
  __syncthreads();
  tile_store128(KT + (size_t)p0*C_, ys, tid);
  __syncthreads();
  proj_gemm(wvb, ys, am, mrow, quad, wave);
  __syncthreads();
  tile_store128(VT + (size_t)p0*C_, ys, tid);
}

// ---------- top-K=16 NN, wave-per-point: lane-parallel distances + butterfly extraction ----------
__global__ __launch_bounds__(512) void knn_kernel(const float* __restrict__ xf,
                                                  int* __restrict__ idxout)
{
  __shared__ float cand[3][3*N_];                  // 18 KB, shared by 8 points (same b,t)
  int tid = threadIdx.x;
  int blk = blockIdx.x;
  int row = blk >> 6;                              // (b,t): 64 rows
  int b = row >> 5, t = row & 31;
  int ng = blk & 63;
  for (int i = tid; i < 3*3*N_; i += 512) {        // 9 iters, coalesced
    int ch = i / (3*N_); int m = i - ch*(3*N_);
    int j = m >> 9, nn = m & (N_-1);
    int tt = t - 1 + j; tt = tt < 0 ? 0 : (tt > T_-1 ? T_-1 : tt);
    cand[ch][m] = xf[((size_t)(b*C_+ch)*T_ + tt)*N_ + nn];
  }
  __syncthreads();
  int wave = tid >> 6, lane = tid & 63;
  int n = ng*8 + wave;                             // this wave's point
  float a0 = cand[0][N_+n], a1 = cand[1][N_+n], a2 = cand[2][N_+n];  // self (j=1 slot)
  // lane L owns candidates m = L + 64*j, j=0..23 (stride-64: conflict-free LDS)
  float d[24];
#pragma unroll
  for (int j = 0; j < 24; ++j) {
    int m = lane + (j << 6);
    float dx = a0 - cand[0][m];
    float dy = a1 - cand[1][m];
    float dz = a2 - cand[2][m];
    // exact numpy order, no fma contraction
    d[j] = __fadd_rn(__fadd_rn(__fmul_rn(dx,dx), __fmul_rn(dy,dy)), __fmul_rn(dz,dz));
  }
  int out_m = 0;
#pragma unroll
  for (int r = 0; r < K_; ++r) {
    // local argmin (ascending j scan + strict < keeps lowest index among ties)
    float dl = d[0]; int jl = 0;
#pragma unroll
    for (int j = 1; j < 24; ++j) { bool c = d[j] < dl; dl = c ? d[j] : dl; jl = c ? j : jl; }
    int ml = lane + (jl << 6);
    // wave-wide lex-min (d, m) via butterfly — lowest global index on ties (= top_k)
#pragma unroll
    for (int s = 32; s >= 1; s >>= 1) {
      float dr = __shfl_xor(dl, s, 64);
      int   mr = __shfl_xor(ml, s, 64);
      bool take = (dr < dl) || (dr == dl && mr < ml);
      dl = take ? dr : dl;
      ml = take ? mr : ml;
    }
    if (lane == r) out_m = ml;                     // lane r records round-r winner
    int sel = ((ml & 63) == lane) ? (ml >> 6) : -1; // owner removes the winner
#pragma unroll
    for (int j = 0; j < 24; ++j) if (j == sel) d[j] = 3.0e38f;
  }
  int point = (b*T_ + t)*N_ + n;
  if (lane < K_) idxout[point*K_ + lane] = out_m;
}

// ---------- attention (gather form, bf16) + residual + BN -> hT (aliases QT) ----------
__global__ __launch_bounds__(256) void attn_kernel(
    const int* __restrict__ idxin, const bf16* __restrict__ xTb,
    bf16* qhT /* in: QT, out: hT */, const bf16* __restrict__ KT,
    const bf16* __restrict__ VT,
    const float* __restrict__ gf, const float* __restrict__ bf_,
    const float* __restrict__ mf, const float* __restrict__ vf)
{
  __shared__ int   col_lds[2][16];
  __shared__ float qbuf[2][C_];
  __shared__ bf16  kbuf[2][K_][C_+4];
  __shared__ float e_lds[2][4][16];
  int tid = threadIdx.x;
  int pt = tid >> 7, o = tid & 127;
  int point = blockIdx.x*2 + pt;
  int b = point >> 14; int tn = point & (TN-1); int t = tn >> 9;
  if (o < K_) {
    int m = idxin[point*K_ + o];
    int j = m >> 9, nn = m & (N_-1);
    int tt = t-1+j; tt = tt<0?0:(tt>T_-1?T_-1:tt);
    col_lds[pt][o] = ((b*T_ + tt)*N_ + nn)*C_;
  }
  int self = point*C_;
  qbuf[pt][o] = b2f(qhT[self + o]);                // QT reads done before first sync
  __syncthreads();
  for (int i = tid; i < 2*K_*C_; i += 256) {       // gather 16 K-columns (256B each)
    int pp = i >> 11, rem = i & 2047, k = rem >> 7, oo = rem & 127;
    kbuf[pp][k][oo] = KT[col_lds[pp][k] + oo];
  }
  __syncthreads();
  if (tid < 128) {                                 // one thread per (point, head, k)
    int pp = tid >> 6, j = tid & 63, hd = j >> 4, k = j & 15;
    const float* qp = &qbuf[pp][hd*32];
    const bf16*  kp = &kbuf[pp][k][hd*32];
    float e = 0.f;
#pragma unroll
    for (int d=0; d<32; ++d) e = fmaf(qp[d], b2f(kp[d]), e);
    // energy = q.(Kself - Knb)/sqrt(D); self term is k-constant -> dropped
    e_lds[pp][hd][k] = -e * 0.17677669529663687f;
  }
  __syncthreads();
  int hd = o >> 5;
  float e[16]; float mx = -3e38f;
#pragma unroll
  for (int k=0;k<K_;++k){ e[k]=e_lds[pt][hd][k]; mx=fmaxf(mx,e[k]); }
  float ssum=0.f;
#pragma unroll
  for (int k=0;k<K_;++k){ e[k]=__expf(e[k]-mx); ssum+=e[k]; }
  float inv = 1.f/ssum;
  float acc = b2f(VT[self + o]);                   // agg = Vself - sum attn*Vnb
  for (int k=0;k<K_;++k)
    acc = fmaf(-(e[k]*inv), b2f(VT[col_lds[pt][k] + o]), acc);
  float hv = b2f(xTb[self + o]) + acc;
  float sc = gf[o] / sqrtf(vf[o] + 1e-5f);
  qhT[self + o] = f2b((hv - mf[o])*sc + bf_[o]);   // hT role
}

// ---------- fused MLP via MFMA: y = W2 . leaky_relu(W1 . h) -> out ch 4..131 ----------
__global__ __launch_bounds__(256) void mlp_kernel(const bf16* __restrict__ hT,
                                                  const bf16* __restrict__ w1b,
                                                  const bf16* __restrict__ w2b,
                                                  const int* __restrict__ flag,
                                                  void* out)
{
  __shared__ bf16  hs[64][136];                    // 17.4 KB
  __shared__ bf16  hid[64][520];                   // 66.6 KB
  __shared__ float yf[64][133];                    // 34.0 KB  (total 118 KB)
  int tid = threadIdx.x;
  int p0 = blockIdx.x*64;
  int lane = tid & 63, wave = tid >> 6;
  int mrow = lane & 15, quad = lane >> 4;
#pragma unroll
  for (int it=0; it<4; ++it) {                     // coalesced 16B loads of hT tile
    int flat = (it*256 + tid)*8;
    int p = flat >> 7, c = flat & 127;
    *(short8*)&hs[p][c] = *(const short8*)&hT[(size_t)(p0+p)*C_ + c];
  }
  __syncthreads();
  // ---- stage 1: hid = leaky_relu(H x W1^T); wave w owns otiles 8w..8w+7 ----
  {
    short8 am[4][4];
#pragma unroll
    for (int mt=0;mt<4;++mt)
#pragma unroll
      for (int kq=0;kq<4;++kq)
        am[mt][kq] = *(const short8*)&hs[mt*16 + mrow][kq*32 + quad*8];
    for (int ot = wave*8; ot < wave*8 + 8; ++ot) {
      f32x4 acc[4];
#pragma unroll
      for (int mt=0;mt<4;++mt) acc[mt] = (f32x4){0.f,0.f,0.f,0.f};
#pragma unroll
      for (int kq=0;kq<4;++kq) {
        short8 bfr = *(const short8*)&w1b[(ot*16+mrow)*C_ + kq*32 + quad*8];
#pragma unroll
        for (int mt=0;mt<4;++mt) acc[mt] = MFMA_BF16(am[mt][kq], bfr, acc[mt]);
      }
#pragma unroll
      for (int mt=0;mt<4;++mt)
#pragma unroll
        for (int r=0;r<4;++r) {
          float z = acc[mt][r];
          hid[mt*16 + quad*4 + r][ot*16 + mrow] = f2b(z > 0.f ? z : 0.2f*z);
        }
    }
  }
  __syncthreads();
  // ---- stage 2: Y = hid x W2^T; wave w owns points 16w..16w+15, all 128 outputs ----
  {
    short8 ha[16];
#pragma unroll
    for (int ks=0;ks<16;++ks)
      ha[ks] = *(const short8*)&hid[wave*16 + mrow][ks*32 + quad*8];
#pragma unroll
    for (int otp=0; otp<4; ++otp) {                // 2 independent acc chains
      f32x4 acc0 = (f32x4){0.f,0.f,0.f,0.f};
      f32x4 acc1 = (f32x4){0.f,0.f,0.f,0.f};
#pragma unroll
      for (int ks=0;ks<16;++ks) {
        short8 b0 = *(const short8*)&w2b[((otp*2  )*16+mrow)*HID_ + ks*32 + quad*8];
        short8 b1 = *(const short8*)&w2b[((otp*2+1)*16+mrow)*HID_ + ks*32 + quad*8];
        acc0 = MFMA_BF16(ha[ks], b0, acc0);
        acc1 = MFMA_BF16(ha[ks], b1, acc1);
      }
#pragma unroll
      for (int r=0;r<4;++r) {
        yf[wave*16 + quad*4 + r][(otp*2  )*16 + mrow] = acc0[r];
        yf[wave*16 + quad*4 + r][(otp*2+1)*16 + mrow] = acc1[r];
      }
    }
  }
  __syncthreads();
  // ---- coalesced store (f32 or bf16 out per flag) ----
  bool f32o = (*flag != 0);
  int p = tid & 63;
  int point = p0 + p;
  int b = point >> 14, tn = point & (TN-1);
  size_t obase = (size_t)b*132*TN + tn;
#pragma unroll
  for (int j = 0; j < 32; ++j) {
    int o = (tid >> 6)*32 + j;
    float vv = yf[p][o];
    size_t oi = obase + (size_t)(4+o)*TN;
    if (f32o) ((float*)out)[oi] = vv;
    else      ((bf16*)out)[oi] = f2b(vv);
  }
}

// ---------- passthrough channels 0..3 ----------
__global__ __launch_bounds__(256) void copy_kernel(const float* __restrict__ xf,
                                                   const int* __restrict__ flag,
                                                   void* out)
{
  int i = blockIdx.x*256 + threadIdx.x;            // exactly B*4*TN = 131072
  int b = i >> 16;                                 // 4*TN = 65536
  int r = i & 65535;
  float v = xf[(size_t)b*C_*TN + r];
  size_t oi = (size_t)b*132*TN + r;
  if (*flag) ((float*)out)[oi] = v;                // bit-exact
  else       ((bf16*)out)[oi] = f2b(v);            // exact round-trip
}

extern "C" void kernel_launch(void* const* d_in, const int* in_sizes, int n_in,
                              void* d_out, int out_size, void* d_ws, size_t ws_size,
                              hipStream_t stream)
{
  (void)in_sizes; (void)n_in; (void)out_size; (void)ws_size;
  char* ws = (char*)d_ws;
  const size_t MB = (size_t)1<<20;
  float* xf  = (float*)(ws + 0*MB);      // 16 MB
  bf16*  QT  = (bf16* )(ws + 16*MB);     // 8 MB (becomes hT after attn)
  bf16*  KT  = (bf16* )(ws + 24*MB);     // 8 MB
  bf16*  VT  = (bf16* )(ws + 32*MB);     // 8 MB
  bf16*  xTb = (bf16* )(ws + 40*MB);     // 8 MB
  int*   idxw= (int*  )(ws + 48*MB);     // 2 MB
  bf16*  wqb = (bf16* )(ws + 50*MB);             // 32 KB
  bf16*  wkb = (bf16* )(ws + 50*MB + 0x8000);    // 32 KB
  bf16*  wvb = (bf16* )(ws + 50*MB + 0x10000);   // 32 KB
  bf16*  w1b = (bf16* )(ws + 50*MB + 0x18000);   // 128 KB
  bf16*  w2b = (bf16* )(ws + 50*MB + 0x38000);   // 128 KB
  float* gf  = (float*)(ws + 50*MB + 0x58000);
  float* bf_ = (float*)(ws + 50*MB + 0x58200);
  float* mf  = (float*)(ws + 50*MB + 0x58400);
  float* vf  = (float*)(ws + 50*MB + 0x58600);
  int*  flag = (int*  )(ws + 50*MB + 0x58800);

  detect_kernel <<<dim3(1), dim3(256), 0, stream>>>(d_in[0], flag);
  convert_kernel<<<dim3(17090), dim3(256), 0, stream>>>(
      d_in[0], d_in[1], d_in[2], d_in[3], d_in[4], d_in[5],
      d_in[6], d_in[7], d_in[8], d_in[9], flag,
      xf, wqb, wkb, wvb, w1b, w2b, gf, bf_, mf, vf);
  proj_kernel <<<dim3(PTS/64), dim3(256), 0, stream>>>(xf, wqb, wkb, wvb, xTb, QT, KT, VT);
  knn_kernel  <<<dim3(PTS/8), dim3(512), 0, stream>>>(xf, idxw);
  attn_kernel <<<dim3(PTS/2), dim3(256), 0, stream>>>(idxw, xTb, QT /*->hT*/, KT, VT, gf, bf_, mf, vf);
  mlp_kernel  <<<dim3(PTS/64), dim3(256), 0, stream>>>(QT /*hT*/, w1b, w2b, flag, d_out);
  copy_kernel <<<dim3(B_*4*TN/256), dim3(256), 0, stream>>>(xf, flag, d_out);
}

// Round 6
// 237.791 us; speedup vs baseline: 9.4515x; 1.4288x over previous
//
#include <hip/hip_runtime.h>
#include <hip/hip_bf16.h>

typedef __hip_bfloat16 bf16;
typedef unsigned long long u64;
typedef __attribute__((ext_vector_type(8))) short short8;   // 8 bf16 = MFMA A/B frag
typedef __attribute__((ext_vector_type(4))) float f32x4;    // MFMA C/D frag

#define B_   2
#define C_   128
#define T_   32
#define N_   512
#define K_   16
#define HID_ 512
#define TN   (T_*N_)          // 16384
#define PTS  (B_*T_*N_)       // 32768

#define MFMA_BF16(a,b,c) __builtin_amdgcn_mfma_f32_16x16x32_bf16((a),(b),(c),0,0,0)

__device__ __forceinline__ float b2f(bf16 v){ return __bfloat162float(v); }
__device__ __forceinline__ bf16  f2b(float v){ return __float2bfloat16(v); }

// ---------- dtype detector: f32 data viewed as bf16 has garbage halves ----------
__global__ __launch_bounds__(256) void detect_kernel(const void* __restrict__ x,
                                                     int* __restrict__ flag)
{
  __shared__ int cnt;
  if (threadIdx.x == 0) cnt = 0;
  __syncthreads();
  const unsigned short* u = (const unsigned short*)x;
  int w = 0;
#pragma unroll
  for (int j = 0; j < 8; ++j) {
    unsigned short v = u[threadIdx.x*8 + j];
    int e = (v >> 7) & 0xFF;
    if (e >= 0x89) w++;
  }
  if (w) atomicAdd(&cnt, w);
  __syncthreads();
  if (threadIdx.x == 0) *flag = (cnt > 32) ? 1 : 0;   // 1 = float32 inputs
}

__device__ __forceinline__ float ldc(const void* p, int i, bool f32) {
  return f32 ? ((const float*)p)[i] : b2f(((const bf16*)p)[i]);
}

// ---------- convert weights + bn only (x stays raw; readers branch on flag) ----------
__global__ __launch_bounds__(256) void convw_kernel(
    const void* wq, const void* wk, const void* wv,
    const void* w1, const void* w2, const void* g, const void* bb,
    const void* m, const void* v, const int* __restrict__ flag,
    bf16* __restrict__ wqb, bf16* __restrict__ wkb, bf16* __restrict__ wvb,
    bf16* __restrict__ w1b, bf16* __restrict__ w2b,
    float* __restrict__ gf, float* __restrict__ bf_, float* __restrict__ mf,
    float* __restrict__ vf)
{
  bool f32 = (*flag != 0);
  int i = blockIdx.x*256 + threadIdx.x;            // grid covers 180736 exactly
  if (i < 16384) { wqb[i] = f2b(ldc(wq, i, f32)); return; } i -= 16384;
  if (i < 16384) { wkb[i] = f2b(ldc(wk, i, f32)); return; } i -= 16384;
  if (i < 16384) { wvb[i] = f2b(ldc(wv, i, f32)); return; } i -= 16384;
  if (i < 65536) { w1b[i] = f2b(ldc(w1, i, f32)); return; } i -= 65536;
  if (i < 65536) { w2b[i] = f2b(ldc(w2, i, f32)); return; } i -= 65536;
  if (i < 128)   { gf[i]  = ldc(g, i, f32); return; }       i -= 128;
  if (i < 128)   { bf_[i] = ldc(bb, i, f32); return; }      i -= 128;
  if (i < 128)   { mf[i]  = ldc(m, i, f32); return; }       i -= 128;
  if (i < 128)   { vf[i]  = ldc(v, i, f32); return; }
}

// ---------- MFMA GEMM helper: D[p][o] += A[p][c]*W[o][c] ----------
__device__ __forceinline__ void proj_gemm(const bf16* __restrict__ W,
                                          bf16 (*ys)[136],
                                          const short8 am[4][4],
                                          int mrow, int quad, int wave)
{
#pragma unroll
  for (int oi = 0; oi < 2; ++oi) {
    int ot = wave*2 + oi;
    f32x4 acc[4];
#pragma unroll
    for (int mt=0;mt<4;++mt) acc[mt] = (f32x4){0.f,0.f,0.f,0.f};
#pragma unroll
    for (int kq=0;kq<4;++kq) {
      short8 bfr = *(const short8*)&W[(ot*16+mrow)*C_ + kq*32 + quad*8];
#pragma unroll
      for (int mt=0;mt<4;++mt) acc[mt] = MFMA_BF16(am[mt][kq], bfr, acc[mt]);
    }
#pragma unroll
    for (int mt=0;mt<4;++mt)
#pragma unroll
      for (int r=0;r<4;++r)
        ys[mt*16 + quad*4 + r][ot*16 + mrow] = f2b(acc[mt][r]);
  }
}

__device__ __forceinline__ void tile_store128(bf16* __restrict__ dst,
                                              const bf16 (*ys)[136], int tid)
{
#pragma unroll
  for (int it=0; it<4; ++it) {
    int flat = (it*256 + tid)*8;
    int p = flat >> 7, c = flat & 127;
    *(short8*)&dst[(size_t)p*C_ + c] = *(const short8*)&ys[p][c];
  }
}

// ---------- QKV projections (MFMA) + point-major bf16 copy of x ----------
__global__ __launch_bounds__(256) void proj_kernel(
    const void* __restrict__ x, const int* __restrict__ flag,
    const bf16* __restrict__ wqb, const bf16* __restrict__ wkb, const bf16* __restrict__ wvb,
    bf16* __restrict__ xTb, bf16* QT, bf16* __restrict__ KT, bf16* __restrict__ VT)
{
  __shared__ bf16 xs[64][136];                     // A-tile [point][c], 17.4 KB
  __shared__ bf16 ys[64][136];                     // D-tile staging, 17.4 KB
  int tid = threadIdx.x;
  int p0  = blockIdx.x * 64;
  int b   = p0 >> 14; int tn0 = p0 & (TN-1);
  if (*flag) {                                     // f32 inputs
    const float* xbase = (const float*)x + (size_t)b*C_*TN + tn0;
#pragma unroll
    for (int it=0; it<32; ++it) {
      int i = it*256 + tid;
      int c = i >> 6, p = i & 63;                  // coalesced over n
      xs[p][c] = f2b(xbase[(size_t)c*TN + p]);
    }
  } else {                                         // bf16 inputs (bit-exact stage)
    const bf16* xbase = (const bf16*)x + (size_t)b*C_*TN + tn0;
#pragma unroll
    for (int it=0; it<32; ++it) {
      int i = it*256 + tid;
      int c = i >> 6, p = i & 63;
      xs[p][c] = xbase[(size_t)c*TN + p];
    }
  }
  __syncthreads();
  tile_store128(xTb + (size_t)p0*C_, xs, tid);     // point-major bf16 x
  int lane = tid & 63, wave = tid >> 6;
  int mrow = lane & 15, quad = lane >> 4;
  short8 am[4][4];
#pragma unroll
  for (int mt=0;mt<4;++mt)
#pragma unroll
    for (int kq=0;kq<4;++kq)
      am[mt][kq] = *(const short8*)&xs[mt*16 + mrow][kq*32 + quad*8];

  proj_gemm(wqb, ys, am, mrow, quad, wave);
  __syncthreads();
  tile_store128(QT + (size_t)p0*C_, ys, tid);
  __syncthreads();
  proj_gemm(wkb, ys, am, mrow, quad, wave);
  __syncthreads();
  tile_store128(KT + (size_t)p0*C_, ys, tid);
  __syncthreads();
  proj_gemm(wvb, ys, am, mrow, quad, wave);
  __syncthreads();
  tile_store128(VT + (size_t)p0*C_, ys, tid);
}

// ---------- wave-ascending bitonic sort of one u64 key per lane ----------
__device__ __forceinline__ u64 shflx64(u64 v, int m) {
  return (u64)__shfl_xor((long long)v, m, 64);
}
__device__ __forceinline__ u64 bitonic64(u64 key, int lane) {
#pragma unroll
  for (int k = 2; k <= 64; k <<= 1) {
#pragma unroll
    for (int j = k >> 1; j >= 1; j >>= 1) {
      u64 p = shflx64(key, j);
      bool keep_min = ((lane & k) == 0) == ((lane & j) == 0);
      bool pl = p < key;
      key = (pl == keep_min) ? p : key;
    }
  }
  return key;
}

// ---------- top-K=16 NN v3: prune-to-survivors (U = 16th lane-min) + bitonic sort ----------
// key = (f32 distance bits << 32) | m : exact lex order == top_k (ties -> lowest m)
__global__ __launch_bounds__(512) void knn_kernel(const void* __restrict__ x,
                                                  const int* __restrict__ flag,
                                                  int* __restrict__ idxout)
{
  __shared__ float cand[3][3*N_];                  // 18 KB, shared by 8 points
  __shared__ u64 surv[8][64];                      // 4 KB
  int tid = threadIdx.x;
  int blk = blockIdx.x;
  int row = blk >> 6;                              // (b,t)
  int b = row >> 5, t = row & 31;
  int ng = blk & 63;
  if (*flag) {
    const float* xp = (const float*)x;
    for (int i = tid; i < 9*N_; i += 512) {
      int ch = i / (3*N_); int m = i - ch*(3*N_);
      int j = m >> 9, nn = m & (N_-1);
      int tt = t - 1 + j; tt = tt < 0 ? 0 : (tt > T_-1 ? T_-1 : tt);
      cand[ch][m] = xp[((size_t)(b*C_+ch)*T_ + tt)*N_ + nn];
    }
  } else {
    const bf16* xp = (const bf16*)x;
    for (int i = tid; i < 9*N_; i += 512) {
      int ch = i / (3*N_); int m = i - ch*(3*N_);
      int j = m >> 9, nn = m & (N_-1);
      int tt = t - 1 + j; tt = tt < 0 ? 0 : (tt > T_-1 ? T_-1 : tt);
      cand[ch][m] = b2f(xp[((size_t)(b*C_+ch)*T_ + tt)*N_ + nn]);
    }
  }
  __syncthreads();
  int wave = tid >> 6, lane = tid & 63;
  int n = ng*8 + wave;                             // this wave's point
  float a0 = cand[0][N_+n], a1 = cand[1][N_+n], a2 = cand[2][N_+n];
  u64 key[24];                                     // lane owns m = lane + 64j
#pragma unroll
  for (int j = 0; j < 24; ++j) {
    int m = lane + (j << 6);
    float dx = a0 - cand[0][m];
    float dy = a1 - cand[1][m];
    float dz = a2 - cand[2][m];
    // exact numpy order, no fma contraction
    float d2 = __fadd_rn(__fadd_rn(__fmul_rn(dx,dx), __fmul_rn(dy,dy)), __fmul_rn(dz,dz));
    key[j] = ((u64)__float_as_uint(d2) << 32) | (unsigned)m;
  }
  // per-lane min
  u64 mn = key[0];
#pragma unroll
  for (int j = 1; j < 24; ++j) mn = (key[j] < mn) ? key[j] : mn;
  // U = 16th smallest lane-min (rank 15 after ascending sort). Any key > U has
  // >=16 distinct smaller keys -> rank >= 17 -> prunable. Survivors contain top-16.
  u64 smin = bitonic64(mn, lane);
  u64 U = (u64)__shfl((long long)smin, 15, 64);
  int c = 0;
#pragma unroll
  for (int j = 0; j < 24; ++j) c += (key[j] <= U) ? 1 : 0;
  int sc = c;                                      // inclusive wave prefix sum
#pragma unroll
  for (int d = 1; d < 64; d <<= 1) {
    int pv = __shfl_up(sc, d, 64);
    if (lane >= d) sc += pv;
  }
  int total = __shfl(sc, 63, 64);
  int ofs = sc - c;                                // exclusive prefix
  u64 out16;
  if (total <= 64) {                               // ~always (E[total] ~ 18)
#pragma unroll
    for (int j = 0; j < 24; ++j) {
      if (key[j] <= U) { surv[wave][ofs] = key[j]; ++ofs; }
    }
    __threadfence_block();
    u64 kk = (lane < total) ? surv[wave][lane] : ~0ull;
    out16 = bitonic64(kk, lane);                   // lanes 0..15 = exact top-16, sorted
  } else {
    // exact fallback: 16 extraction rounds (same semantics)
    u64 res = ~0ull;
#pragma unroll 1
    for (int r = 0; r < 16; ++r) {
      u64 m2 = key[0];
#pragma unroll
      for (int j = 1; j < 24; ++j) m2 = (key[j] < m2) ? key[j] : m2;
#pragma unroll
      for (int s = 32; s >= 1; s >>= 1) {
        u64 p = shflx64(m2, s);
        m2 = (p < m2) ? p : m2;
      }
      if (lane == r) res = m2;
      int mwin = (int)(m2 & 0xffffffffu);
      int sel = ((mwin & 63) == lane) ? (mwin >> 6) : -1;
#pragma unroll
      for (int j = 0; j < 24; ++j) if (j == sel) key[j] = ~0ull;
    }
    out16 = res;
  }
  int point = (b*T_ + t)*N_ + n;
  if (lane < K_) idxout[point*K_ + lane] = (int)(out16 & 0xffffffffu);
}

// ---------- attention (gather form, bf16, 16B gathers) + residual + BN -> hT ----------
__global__ __launch_bounds__(256) void attn_kernel(
    const int* __restrict__ idxin, const bf16* __restrict__ xTb,
    bf16* qhT /* in: QT, out: hT */, const bf16* __restrict__ KT,
    const bf16* __restrict__ VT,
    const float* __restrict__ gf, const float* __restrict__ bf_,
    const float* __restrict__ mf, const float* __restrict__ vf)
{
  __shared__ int   col_lds[2][16];
  __shared__ float qbuf[2][C_];
  __shared__ bf16  kbuf[2][K_][136];
  __shared__ bf16  vbuf[2][K_][136];
  __shared__ float e_lds[2][4][16];
  int tid = threadIdx.x;
  int pt = tid >> 7, o = tid & 127;
  int point = blockIdx.x*2 + pt;
  int b = point >> 14; int tn = point & (TN-1); int t = tn >> 9;
  if (o < K_) {
    int m = idxin[point*K_ + o];
    int j = m >> 9, nn = m & (N_-1);
    int tt = t-1+j; tt = tt<0?0:(tt>T_-1?T_-1:tt);
    col_lds[pt][o] = ((b*T_ + tt)*N_ + nn)*C_;
  }
  int self = point*C_;
  qbuf[pt][o] = b2f(qhT[self + o]);                // QT reads done before first sync
  __syncthreads();
  // gather 32 K/V columns per block as 16B chunks (coalesced 256B per column)
#pragma unroll
  for (int it = 0; it < 2; ++it) {
    int i = it*256 + tid;
    int pp = i >> 8, rem = i & 255, k = rem >> 4, ch = rem & 15;
    int src = col_lds[pp][k] + ch*8;
    *(short8*)&kbuf[pp][k][ch*8] = *(const short8*)&KT[src];
    *(short8*)&vbuf[pp][k][ch*8] = *(const short8*)&VT[src];
  }
  __syncthreads();
  if (tid < 128) {                                 // one thread per (point, head, k)
    int pp = tid >> 6, j = tid & 63, hd = j >> 4, k = j & 15;
    const float* qp = &qbuf[pp][hd*32];
    const bf16*  kp = &kbuf[pp][k][hd*32];
    float e = 0.f;
#pragma unroll
    for (int d=0; d<32; ++d) e = fmaf(qp[d], b2f(kp[d]), e);
    // energy = q.(Kself - Knb)/sqrt(D); self term k-constant -> dropped
    e_lds[pp][hd][k] = -e * 0.17677669529663687f;
  }
  __syncthreads();
  int hd = o >> 5;
  float e[16]; float mx = -3e38f;
#pragma unroll
  for (int k=0;k<K_;++k){ e[k]=e_lds[pt][hd][k]; mx=fmaxf(mx,e[k]); }
  float ssum=0.f;
#pragma unroll
  for (int k=0;k<K_;++k){ e[k]=__expf(e[k]-mx); ssum+=e[k]; }
  float inv = 1.f/ssum;
  float acc = b2f(VT[self + o]);                   // agg = Vself - sum attn*Vnb
#pragma unroll
  for (int k=0;k<K_;++k)
    acc = fmaf(-(e[k]*inv), b2f(vbuf[pt][k][o]), acc);
  float hv = b2f(xTb[self + o]) + acc;
  float sc = gf[o] / sqrtf(vf[o] + 1e-5f);
  qhT[self + o] = f2b((hv - mf[o])*sc + bf_[o]);   // hT role
}

// ---------- fused MLP via MFMA: y = W2 . leaky_relu(W1 . h) -> out ch 4..131 ----------
__global__ __launch_bounds__(256) void mlp_kernel(const bf16* __restrict__ hT,
                                                  const bf16* __restrict__ w1b,
                                                  const bf16* __restrict__ w2b,
                                                  const int* __restrict__ flag,
                                                  void* out)
{
  __shared__ bf16  hs[64][136];                    // 17.4 KB
  __shared__ bf16  hid[64][520];                   // 66.6 KB
  __shared__ float yf[64][133];                    // 34.0 KB
  int tid = threadIdx.x;
  int p0 = blockIdx.x*64;
  int lane = tid & 63, wave = tid >> 6;
  int mrow = lane & 15, quad = lane >> 4;
#pragma unroll
  for (int it=0; it<4; ++it) {
    int flat = (it*256 + tid)*8;
    int p = flat >> 7, c = flat & 127;
    *(short8*)&hs[p][c] = *(const short8*)&hT[(size_t)(p0+p)*C_ + c];
  }
  __syncthreads();
  {
    short8 am[4][4];
#pragma unroll
    for (int mt=0;mt<4;++mt)
#pragma unroll
      for (int kq=0;kq<4;++kq)
        am[mt][kq] = *(const short8*)&hs[mt*16 + mrow][kq*32 + quad*8];
    for (int ot = wave*8; ot < wave*8 + 8; ++ot) {
      f32x4 acc[4];
#pragma unroll
      for (int mt=0;mt<4;++mt) acc[mt] = (f32x4){0.f,0.f,0.f,0.f};
#pragma unroll
      for (int kq=0;kq<4;++kq) {
        short8 bfr = *(const short8*)&w1b[(ot*16+mrow)*C_ + kq*32 + quad*8];
#pragma unroll
        for (int mt=0;mt<4;++mt) acc[mt] = MFMA_BF16(am[mt][kq], bfr, acc[mt]);
      }
#pragma unroll
      for (int mt=0;mt<4;++mt)
#pragma unroll
        for (int r=0;r<4;++r) {
          float z = acc[mt][r];
          hid[mt*16 + quad*4 + r][ot*16 + mrow] = f2b(z > 0.f ? z : 0.2f*z);
        }
    }
  }
  __syncthreads();
  {
    short8 ha[16];
#pragma unroll
    for (int ks=0;ks<16;++ks)
      ha[ks] = *(const short8*)&hid[wave*16 + mrow][ks*32 + quad*8];
#pragma unroll
    for (int otp=0; otp<4; ++otp) {
      f32x4 acc0 = (f32x4){0.f,0.f,0.f,0.f};
      f32x4 acc1 = (f32x4){0.f,0.f,0.f,0.f};
#pragma unroll
      for (int ks=0;ks<16;++ks) {
        short8 b0 = *(const short8*)&w2b[((otp*2  )*16+mrow)*HID_ + ks*32 + quad*8];
        short8 b1 = *(const short8*)&w2b[((otp*2+1)*16+mrow)*HID_ + ks*32 + quad*8];
        acc0 = MFMA_BF16(ha[ks], b0, acc0);
        acc1 = MFMA_BF16(ha[ks], b1, acc1);
      }
#pragma unroll
      for (int r=0;r<4;++r) {
        yf[wave*16 + quad*4 + r][(otp*2  )*16 + mrow] = acc0[r];
        yf[wave*16 + quad*4 + r][(otp*2+1)*16 + mrow] = acc1[r];
      }
    }
  }
  __syncthreads();
  bool f32o = (*flag != 0);
  int p = tid & 63;
  int point = p0 + p;
  int b = point >> 14, tn = point & (TN-1);
  size_t obase = (size_t)b*132*TN + tn;
#pragma unroll
  for (int j = 0; j < 32; ++j) {
    int o = (tid >> 6)*32 + j;
    float vv = yf[p][o];
    size_t oi = obase + (size_t)(4+o)*TN;
    if (f32o) ((float*)out)[oi] = vv;
    else      ((bf16*)out)[oi] = f2b(vv);
  }
}

// ---------- passthrough channels 0..3 (bit-exact copy from raw x) ----------
__global__ __launch_bounds__(256) void copy_kernel(const void* __restrict__ x,
                                                   const int* __restrict__ flag,
                                                   void* out)
{
  int i = blockIdx.x*256 + threadIdx.x;            // exactly B*4*TN = 131072
  int b = i >> 16;                                 // 4*TN = 65536
  int r = i & 65535;
  if (*flag) ((float*)out)[(size_t)b*132*TN + r] = ((const float*)x)[(size_t)b*C_*TN + r];
  else       ((bf16*)out)[(size_t)b*132*TN + r] = ((const bf16*)x)[(size_t)b*C_*TN + r];
}

extern "C" void kernel_launch(void* const* d_in, const int* in_sizes, int n_in,
                              void* d_out, int out_size, void* d_ws, size_t ws_size,
                              hipStream_t stream)
{
  (void)in_sizes; (void)n_in; (void)out_size; (void)ws_size;
  const void* x = d_in[0];
  char* ws = (char*)d_ws;
  const size_t MB = (size_t)1<<20;
  bf16*  QT  = (bf16* )(ws + 0*MB);      // 8 MB (becomes hT after attn)
  bf16*  KT  = (bf16* )(ws + 8*MB);      // 8 MB
  bf16*  VT  = (bf16* )(ws + 16*MB);     // 8 MB
  bf16*  xTb = (bf16* )(ws + 24*MB);     // 8 MB
  int*   idxw= (int*  )(ws + 32*MB);     // 2 MB
  bf16*  wqb = (bf16* )(ws + 34*MB);             // 32 KB
  bf16*  wkb = (bf16* )(ws + 34*MB + 0x8000);    // 32 KB
  bf16*  wvb = (bf16* )(ws + 34*MB + 0x10000);   // 32 KB
  bf16*  w1b = (bf16* )(ws + 34*MB + 0x18000);   // 128 KB
  bf16*  w2b = (bf16* )(ws + 34*MB + 0x38000);   // 128 KB
  float* gf  = (float*)(ws + 34*MB + 0x58000);
  float* bf_ = (float*)(ws + 34*MB + 0x58200);
  float* mf  = (float*)(ws + 34*MB + 0x58400);
  float* vf  = (float*)(ws + 34*MB + 0x58600);
  int*  flag = (int*  )(ws + 34*MB + 0x58800);

  detect_kernel<<<dim3(1), dim3(256), 0, stream>>>(x, flag);
  convw_kernel <<<dim3(706), dim3(256), 0, stream>>>(
      d_in[1], d_in[2], d_in[3], d_in[4], d_in[5],
      d_in[6], d_in[7], d_in[8], d_in[9], flag,
      wqb, wkb, wvb, w1b, w2b, gf, bf_, mf, vf);
  proj_kernel <<<dim3(PTS/64), dim3(256), 0, stream>>>(x, flag, wqb, wkb, wvb, xTb, QT, KT, VT);
  knn_kernel  <<<dim3(PTS/8), dim3(512), 0, stream>>>(x, flag, idxw);
  attn_kernel <<<dim3(PTS/2), dim3(256), 0, stream>>>(idxw, xTb, QT /*->hT*/, KT, VT, gf, bf_, mf, vf);
  mlp_kernel  <<<dim3(PTS/64), dim3(256), 0, stream>>>(QT /*hT*/, w1b, w2b, flag, d_out);
  copy_kernel <<<dim3(B_*4*TN/256), dim3(256), 0, stream>>>(x, flag, d_out);
}

// Round 7
// 236.526 us; speedup vs baseline: 9.5021x; 1.0053x over previous
//
#include <hip/hip_runtime.h>
#include <hip/hip_bf16.h>

typedef __hip_bfloat16 bf16;
typedef unsigned long long u64;
typedef __attribute__((ext_vector_type(8))) short short8;   // 8 bf16 = MFMA A/B frag
typedef __attribute__((ext_vector_type(4))) float f32x4;    // MFMA C/D frag

#define B_   2
#define C_   128
#define T_   32
#define N_   512
#define K_   16
#define HID_ 512
#define TN   (T_*N_)          // 16384
#define PTS  (B_*T_*N_)       // 32768

#define MFMA_BF16(a,b,c) __builtin_amdgcn_mfma_f32_16x16x32_bf16((a),(b),(c),0,0,0)

__device__ __forceinline__ float b2f(bf16 v){ return __bfloat162float(v); }
__device__ __forceinline__ bf16  f2b(float v){ return __float2bfloat16(v); }

__device__ __forceinline__ float ldc(const void* p, int i, bool f32) {
  return f32 ? ((const float*)p)[i] : b2f(((const bf16*)p)[i]);
}

// ---------- convert weights + bn; every block locally detects input dtype; blk0 publishes flag ----------
__global__ __launch_bounds__(256) void convw_kernel(
    const void* __restrict__ x,
    const void* wq, const void* wk, const void* wv,
    const void* w1, const void* w2, const void* g, const void* bb,
    const void* m, const void* v,
    bf16* __restrict__ wqb, bf16* __restrict__ wkb, bf16* __restrict__ wvb,
    bf16* __restrict__ w1b, bf16* __restrict__ w2b,
    float* __restrict__ gf, float* __restrict__ bf_, float* __restrict__ mf,
    float* __restrict__ vf, int* __restrict__ flag)
{
  // dtype detect: f32 data viewed as 16-bit halves has ~46% garbage exponents
  __shared__ int cnt;
  if (threadIdx.x == 0) cnt = 0;
  __syncthreads();
  const unsigned short* u = (const unsigned short*)x;
  int w = 0;
#pragma unroll
  for (int j = 0; j < 8; ++j) {
    unsigned short hv = u[threadIdx.x*8 + j];
    int e = (hv >> 7) & 0xFF;
    if (e >= 0x89) w++;
  }
  if (w) atomicAdd(&cnt, w);
  __syncthreads();
  bool f32 = (cnt > 32);
  if (blockIdx.x == 0 && threadIdx.x == 0) *flag = f32 ? 1 : 0;

  int i = blockIdx.x*256 + threadIdx.x;            // grid covers 180736 exactly
  if (i < 16384) { wqb[i] = f2b(ldc(wq, i, f32)); return; } i -= 16384;
  if (i < 16384) { wkb[i] = f2b(ldc(wk, i, f32)); return; } i -= 16384;
  if (i < 16384) { wvb[i] = f2b(ldc(wv, i, f32)); return; } i -= 16384;
  if (i < 65536) { w1b[i] = f2b(ldc(w1, i, f32)); return; } i -= 65536;
  if (i < 65536) { w2b[i] = f2b(ldc(w2, i, f32)); return; } i -= 65536;
  if (i < 128)   { gf[i]  = ldc(g, i, f32); return; }       i -= 128;
  if (i < 128)   { bf_[i] = ldc(bb, i, f32); return; }      i -= 128;
  if (i < 128)   { mf[i]  = ldc(m, i, f32); return; }       i -= 128;
  if (i < 128)   { vf[i]  = ldc(v, i, f32); return; }
}

// ---------- MFMA GEMM helper: D[p][o] += A[p][c]*W[o][c] ----------
__device__ __forceinline__ void proj_gemm(const bf16* __restrict__ W,
                                          bf16 (*ys)[136],
                                          const short8 am[4][4],
                                          int mrow, int quad, int wave)
{
#pragma unroll
  for (int oi = 0; oi < 2; ++oi) {
    int ot = wave*2 + oi;
    f32x4 acc[4];
#pragma unroll
    for (int mt=0;mt<4;++mt) acc[mt] = (f32x4){0.f,0.f,0.f,0.f};
#pragma unroll
    for (int kq=0;kq<4;++kq) {
      short8 bfr = *(const short8*)&W[(ot*16+mrow)*C_ + kq*32 + quad*8];
#pragma unroll
      for (int mt=0;mt<4;++mt) acc[mt] = MFMA_BF16(am[mt][kq], bfr, acc[mt]);
    }
#pragma unroll
    for (int mt=0;mt<4;++mt)
#pragma unroll
      for (int r=0;r<4;++r)
        ys[mt*16 + quad*4 + r][ot*16 + mrow] = f2b(acc[mt][r]);
  }
}

__device__ __forceinline__ void tile_store128(bf16* __restrict__ dst,
                                              const bf16 (*ys)[136], int tid)
{
#pragma unroll
  for (int it=0; it<4; ++it) {
    int flat = (it*256 + tid)*8;
    int p = flat >> 7, c = flat & 127;
    *(short8*)&dst[(size_t)p*C_ + c] = *(const short8*)&ys[p][c];
  }
}

// ---------- QKV projections (MFMA, batched stores) + point-major bf16 copy of x ----------
__global__ __launch_bounds__(256) void proj_kernel(
    const void* __restrict__ x, const int* __restrict__ flag,
    const bf16* __restrict__ wqb, const bf16* __restrict__ wkb, const bf16* __restrict__ wvb,
    bf16* __restrict__ xTb, bf16* QT, bf16* __restrict__ KT, bf16* __restrict__ VT)
{
  __shared__ bf16 xs [64][136];                    // A-tile; reused as Q D-tile
  __shared__ bf16 ysK[64][136];
  __shared__ bf16 ysV[64][136];                    // 52.2 KB total -> 3 blocks/CU
  int tid = threadIdx.x;
  int p0  = blockIdx.x * 64;
  int b   = p0 >> 14; int tn0 = p0 & (TN-1);
  if (*flag) {                                     // f32 inputs
    const float* xbase = (const float*)x + (size_t)b*C_*TN + tn0;
#pragma unroll
    for (int it=0; it<32; ++it) {
      int i = it*256 + tid;
      int c = i >> 6, p = i & 63;                  // coalesced over n
      xs[p][c] = f2b(xbase[(size_t)c*TN + p]);
    }
  } else {                                         // bf16 inputs (bit-exact stage)
    const bf16* xbase = (const bf16*)x + (size_t)b*C_*TN + tn0;
#pragma unroll
    for (int it=0; it<32; ++it) {
      int i = it*256 + tid;
      int c = i >> 6, p = i & 63;
      xs[p][c] = xbase[(size_t)c*TN + p];
    }
  }
  __syncthreads();
  tile_store128(xTb + (size_t)p0*C_, xs, tid);     // point-major bf16 x (reads xs)
  int lane = tid & 63, wave = tid >> 6;
  int mrow = lane & 15, quad = lane >> 4;
  short8 am[4][4];                                 // A-frags (reads xs)
#pragma unroll
  for (int mt=0;mt<4;++mt)
#pragma unroll
    for (int kq=0;kq<4;++kq)
      am[mt][kq] = *(const short8*)&xs[mt*16 + mrow][kq*32 + quad*8];
  __syncthreads();                                 // all xs reads done; xs becomes ysQ
  proj_gemm(wqb, xs,  am, mrow, quad, wave);
  proj_gemm(wkb, ysK, am, mrow, quad, wave);
  proj_gemm(wvb, ysV, am, mrow, quad, wave);
  __syncthreads();
  tile_store128(QT + (size_t)p0*C_, xs,  tid);
  tile_store128(KT + (size_t)p0*C_, ysK, tid);
  tile_store128(VT + (size_t)p0*C_, ysV, tid);
}

// ---------- wave-ascending bitonic sort of one u64 key per lane ----------
__device__ __forceinline__ u64 shflx64(u64 v, int m) {
  return (u64)__shfl_xor((long long)v, m, 64);
}
__device__ __forceinline__ u64 bitonic64(u64 key, int lane) {
#pragma unroll
  for (int k = 2; k <= 64; k <<= 1) {
#pragma unroll
    for (int j = k >> 1; j >= 1; j >>= 1) {
      u64 p = shflx64(key, j);
      bool keep_min = ((lane & k) == 0) == ((lane & j) == 0);
      bool pl = p < key;
      key = (pl == keep_min) ? p : key;
    }
  }
  return key;
}

// ---------- top-K=16 NN: prune-to-survivors (U = 16th lane-min) + bitonic sort ----------
// key = (f32 distance bits << 32) | m : exact lex order == top_k (ties -> lowest m)
__global__ __launch_bounds__(512) void knn_kernel(const void* __restrict__ x,
                                                  const int* __restrict__ flag,
                                                  int* __restrict__ idxout)
{
  __shared__ float cand[3][3*N_];                  // 18 KB, shared by 8 points
  __shared__ u64 surv[8][64];                      // 4 KB
  int tid = threadIdx.x;
  int blk = blockIdx.x;
  int row = blk >> 6;                              // (b,t)
  int b = row >> 5, t = row & 31;
  int ng = blk & 63;
  if (*flag) {
    const float* xp = (const float*)x;
    for (int i = tid; i < 9*N_; i += 512) {
      int ch = i / (3*N_); int m = i - ch*(3*N_);
      int j = m >> 9, nn = m & (N_-1);
      int tt = t - 1 + j; tt = tt < 0 ? 0 : (tt > T_-1 ? T_-1 : tt);
      cand[ch][m] = xp[((size_t)(b*C_+ch)*T_ + tt)*N_ + nn];
    }
  } else {
    const bf16* xp = (const bf16*)x;
    for (int i = tid; i < 9*N_; i += 512) {
      int ch = i / (3*N_); int m = i - ch*(3*N_);
      int j = m >> 9, nn = m & (N_-1);
      int tt = t - 1 + j; tt = tt < 0 ? 0 : (tt > T_-1 ? T_-1 : tt);
      cand[ch][m] = b2f(xp[((size_t)(b*C_+ch)*T_ + tt)*N_ + nn]);
    }
  }
  __syncthreads();
  int wave = tid >> 6, lane = tid & 63;
  int n = ng*8 + wave;                             // this wave's point
  float a0 = cand[0][N_+n], a1 = cand[1][N_+n], a2 = cand[2][N_+n];
  u64 key[24];                                     // lane owns m = lane + 64j
#pragma unroll
  for (int j = 0; j < 24; ++j) {
    int m = lane + (j << 6);
    float dx = a0 - cand[0][m];
    float dy = a1 - cand[1][m];
    float dz = a2 - cand[2][m];
    // exact numpy order, no fma contraction
    float d2 = __fadd_rn(__fadd_rn(__fmul_rn(dx,dx), __fmul_rn(dy,dy)), __fmul_rn(dz,dz));
    key[j] = ((u64)__float_as_uint(d2) << 32) | (unsigned)m;
  }
  u64 mn = key[0];
#pragma unroll
  for (int j = 1; j < 24; ++j) mn = (key[j] < mn) ? key[j] : mn;
  // U = 16th smallest lane-min: any key > U has >=16 smaller keys -> prunable
  u64 smin = bitonic64(mn, lane);
  u64 U = (u64)__shfl((long long)smin, 15, 64);
  int c = 0;
#pragma unroll
  for (int j = 0; j < 24; ++j) c += (key[j] <= U) ? 1 : 0;
  int sc = c;                                      // inclusive wave prefix sum
#pragma unroll
  for (int d = 1; d < 64; d <<= 1) {
    int pv = __shfl_up(sc, d, 64);
    if (lane >= d) sc += pv;
  }
  int total = __shfl(sc, 63, 64);
  int ofs = sc - c;
  u64 out16;
  if (total <= 64) {                               // ~always (E[total] ~ 18)
#pragma unroll
    for (int j = 0; j < 24; ++j) {
      if (key[j] <= U) { surv[wave][ofs] = key[j]; ++ofs; }
    }
    __threadfence_block();
    u64 kk = (lane < total) ? surv[wave][lane] : ~0ull;
    out16 = bitonic64(kk, lane);                   // lanes 0..15 = exact top-16, sorted
  } else {
    u64 res = ~0ull;                               // exact fallback
#pragma unroll 1
    for (int r = 0; r < 16; ++r) {
      u64 m2 = key[0];
#pragma unroll
      for (int j = 1; j < 24; ++j) m2 = (key[j] < m2) ? key[j] : m2;
#pragma unroll
      for (int s = 32; s >= 1; s >>= 1) {
        u64 p = shflx64(m2, s);
        m2 = (p < m2) ? p : m2;
      }
      if (lane == r) res = m2;
      int mwin = (int)(m2 & 0xffffffffu);
      int sel = ((mwin & 63) == lane) ? (mwin >> 6) : -1;
#pragma unroll
      for (int j = 0; j < 24; ++j) if (j == sel) key[j] = ~0ull;
    }
    out16 = res;
  }
  int point = (b*T_ + t)*N_ + n;
  if (lane < K_) idxout[point*K_ + lane] = (int)(out16 & 0xffffffffu);
}

// ---------- attention: 4 points / 512-thread block ----------
__global__ __launch_bounds__(512) void attn_kernel(
    const int* __restrict__ idxin, const bf16* __restrict__ xTb,
    bf16* qhT /* in: QT, out: hT */, const bf16* __restrict__ KT,
    const bf16* __restrict__ VT,
    const float* __restrict__ gf, const float* __restrict__ bf_,
    const float* __restrict__ mf, const float* __restrict__ vf)
{
  __shared__ int   col_lds[4][16];
  __shared__ float qbuf[4][C_];
  __shared__ bf16  kbuf[4][K_][136];
  __shared__ bf16  vbuf[4][K_][136];               // ~38 KB total
  __shared__ float e_lds[4][4][16];
  int tid = threadIdx.x;
  int pt = tid >> 7, o = tid & 127;
  int point = blockIdx.x*4 + pt;
  int b = point >> 14; int tn = point & (TN-1); int t = tn >> 9;
  if (o < K_) {
    int m = idxin[point*K_ + o];
    int j = m >> 9, nn = m & (N_-1);
    int tt = t-1+j; tt = tt<0?0:(tt>T_-1?T_-1:tt);
    col_lds[pt][o] = ((b*T_ + tt)*N_ + nn)*C_;
  }
  int self = point*C_;
  qbuf[pt][o] = b2f(qhT[self + o]);                // QT reads done before first sync
  __syncthreads();
  // gather 64 K/V columns per block as 16B chunks (coalesced 256B per column)
#pragma unroll
  for (int it = 0; it < 2; ++it) {
    int i = it*512 + tid;
    int pp = i >> 8, rem = i & 255, k = rem >> 4, ch = rem & 15;
    int src = col_lds[pp][k] + ch*8;
    *(short8*)&kbuf[pp][k][ch*8] = *(const short8*)&KT[src];
    *(short8*)&vbuf[pp][k][ch*8] = *(const short8*)&VT[src];
  }
  __syncthreads();
  if (tid < 256) {                                 // one thread per (point, head, k)
    int pp = tid >> 6, j = tid & 63, hd = j >> 4, k = j & 15;
    const float* qp = &qbuf[pp][hd*32];
    const bf16*  kp = &kbuf[pp][k][hd*32];
    float e = 0.f;
#pragma unroll
    for (int d=0; d<32; ++d) e = fmaf(qp[d], b2f(kp[d]), e);
    // energy = q.(Kself - Knb)/sqrt(D); self term k-constant -> dropped
    e_lds[pp][hd][k] = -e * 0.17677669529663687f;
  }
  __syncthreads();
  int hd = o >> 5;
  float e[16]; float mx = -3e38f;
#pragma unroll
  for (int k=0;k<K_;++k){ e[k]=e_lds[pt][hd][k]; mx=fmaxf(mx,e[k]); }
  float ssum=0.f;
#pragma unroll
  for (int k=0;k<K_;++k){ e[k]=__expf(e[k]-mx); ssum+=e[k]; }
  float inv = 1.f/ssum;
  float acc = b2f(VT[self + o]);                   // agg = Vself - sum attn*Vnb
#pragma unroll
  for (int k=0;k<K_;++k)
    acc = fmaf(-(e[k]*inv), b2f(vbuf[pt][k][o]), acc);
  float hv = b2f(xTb[self + o]) + acc;
  float sc = gf[o] / sqrtf(vf[o] + 1e-5f);
  qhT[self + o] = f2b((hv - mf[o])*sc + bf_[o]);   // hT role
}

// ---------- fused MLP via MFMA + passthrough ch 0..3 -> all 132 out channels ----------
__global__ __launch_bounds__(256) void mlp_kernel(const bf16* __restrict__ hT,
                                                  const bf16* __restrict__ w1b,
                                                  const bf16* __restrict__ w2b,
                                                  const void* __restrict__ x,
                                                  const int* __restrict__ flag,
                                                  void* out)
{
  __shared__ bf16  hs[64][136];                    // 17.4 KB
  __shared__ bf16  hid[64][520];                   // 66.6 KB
  __shared__ float yf[64][133];                    // 34.0 KB
  int tid = threadIdx.x;
  int p0 = blockIdx.x*64;
  int lane = tid & 63, wave = tid >> 6;
  int mrow = lane & 15, quad = lane >> 4;
  bool f32o = (*flag != 0);
  {                                                // passthrough ch 0..3 for this tile
    int c = tid >> 6, p = tid & 63;
    int pnt = p0 + p;
    int bb = pnt >> 14, tn = pnt & (TN-1);
    size_t si = ((size_t)bb*C_ + c)*TN + tn;
    size_t di = ((size_t)bb*132 + c)*TN + tn;
    if (f32o) ((float*)out)[di] = ((const float*)x)[si];
    else      ((bf16*)out)[di] = ((const bf16*)x)[si];
  }
#pragma unroll
  for (int it=0; it<4; ++it) {
    int flat = (it*256 + tid)*8;
    int p = flat >> 7, c = flat & 127;
    *(short8*)&hs[p][c] = *(const short8*)&hT[(size_t)(p0+p)*C_ + c];
  }
  __syncthreads();
  {
    short8 am[4][4];
#pragma unroll
    for (int mt=0;mt<4;++mt)
#pragma unroll
      for (int kq=0;kq<4;++kq)
        am[mt][kq] = *(const short8*)&hs[mt*16 + mrow][kq*32 + quad*8];
    for (int ot = wave*8; ot < wave*8 + 8; ++ot) {
      f32x4 acc[4];
#pragma unroll
      for (int mt=0;mt<4;++mt) acc[mt] = (f32x4){0.f,0.f,0.f,0.f};
#pragma unroll
      for (int kq=0;kq<4;++kq) {
        short8 bfr = *(const short8*)&w1b[(ot*16+mrow)*C_ + kq*32 + quad*8];
#pragma unroll
        for (int mt=0;mt<4;++mt) acc[mt] = MFMA_BF16(am[mt][kq], bfr, acc[mt]);
      }
#pragma unroll
      for (int mt=0;mt<4;++mt)
#pragma unroll
        for (int r=0;r<4;++r) {
          float z = acc[mt][r];
          hid[mt*16 + quad*4 + r][ot*16 + mrow] = f2b(z > 0.f ? z : 0.2f*z);
        }
    }
  }
  __syncthreads();
  {
    short8 ha[16];
#pragma unroll
    for (int ks=0;ks<16;++ks)
      ha[ks] = *(const short8*)&hid[wave*16 + mrow][ks*32 + quad*8];
#pragma unroll
    for (int otp=0; otp<4; ++otp) {
      f32x4 acc0 = (f32x4){0.f,0.f,0.f,0.f};
      f32x4 acc1 = (f32x4){0.f,0.f,0.f,0.f};
#pragma unroll
      for (int ks=0;ks<16;++ks) {
        short8 b0 = *(const short8*)&w2b[((otp*2  )*16+mrow)*HID_ + ks*32 + quad*8];
        short8 b1 = *(const short8*)&w2b[((otp*2+1)*16+mrow)*HID_ + ks*32 + quad*8];
        acc0 = MFMA_BF16(ha[ks], b0, acc0);
        acc1 = MFMA_BF16(ha[ks], b1, acc1);
      }
#pragma unroll
      for (int r=0;r<4;++r) {
        yf[wave*16 + quad*4 + r][(otp*2  )*16 + mrow] = acc0[r];
        yf[wave*16 + quad*4 + r][(otp*2+1)*16 + mrow] = acc1[r];
      }
    }
  }
  __syncthreads();
  int p = tid & 63;
  int point = p0 + p;
  int b = point >> 14, tn = point & (TN-1);
  size_t obase = (size_t)b*132*TN + tn;
#pragma unroll
  for (int j = 0; j < 32; ++j) {
    int o = (tid >> 6)*32 + j;
    float vv = yf[p][o];
    size_t oi = obase + (size_t)(4+o)*TN;
    if (f32o) ((float*)out)[oi] = vv;
    else      ((bf16*)out)[oi] = f2b(vv);
  }
}

extern "C" void kernel_launch(void* const* d_in, const int* in_sizes, int n_in,
                              void* d_out, int out_size, void* d_ws, size_t ws_size,
                              hipStream_t stream)
{
  (void)in_sizes; (void)n_in; (void)out_size; (void)ws_size;
  const void* x = d_in[0];
  char* ws = (char*)d_ws;
  const size_t MB = (size_t)1<<20;
  bf16*  QT  = (bf16* )(ws + 0*MB);      // 8 MB (becomes hT after attn)
  bf16*  KT  = (bf16* )(ws + 8*MB);      // 8 MB
  bf16*  VT  = (bf16* )(ws + 16*MB);     // 8 MB
  bf16*  xTb = (bf16* )(ws + 24*MB);     // 8 MB
  int*   idxw= (int*  )(ws + 32*MB);     // 2 MB
  bf16*  wqb = (bf16* )(ws + 34*MB);             // 32 KB
  bf16*  wkb = (bf16* )(ws + 34*MB + 0x8000);    // 32 KB
  bf16*  wvb = (bf16* )(ws + 34*MB + 0x10000);   // 32 KB
  bf16*  w1b = (bf16* )(ws + 34*MB + 0x18000);   // 128 KB
  bf16*  w2b = (bf16* )(ws + 34*MB + 0x38000);   // 128 KB
  float* gf  = (float*)(ws + 34*MB + 0x58000);
  float* bf_ = (float*)(ws + 34*MB + 0x58200);
  float* mf  = (float*)(ws + 34*MB + 0x58400);
  float* vf  = (float*)(ws + 34*MB + 0x58600);
  int*  flag = (int*  )(ws + 34*MB + 0x58800);

  convw_kernel<<<dim3(706), dim3(256), 0, stream>>>(
      x, d_in[1], d_in[2], d_in[3], d_in[4], d_in[5],
      d_in[6], d_in[7], d_in[8], d_in[9],
      wqb, wkb, wvb, w1b, w2b, gf, bf_, mf, vf, flag);
  proj_kernel <<<dim3(PTS/64), dim3(256), 0, stream>>>(x, flag, wqb, wkb, wvb, xTb, QT, KT, VT);
  knn_kernel  <<<dim3(PTS/8), dim3(512), 0, stream>>>(x, flag, idxw);
  attn_kernel <<<dim3(PTS/4), dim3(512), 0, stream>>>(idxw, xTb, QT /*->hT*/, KT, VT, gf, bf_, mf, vf);
  mlp_kernel  <<<dim3(PTS/64), dim3(256), 0, stream>>>(QT /*hT*/, w1b, w2b, x, flag, d_out);
}

// Round 8
// 214.201 us; speedup vs baseline: 10.4924x; 1.1042x over previous
//
#include <hip/hip_runtime.h>
#include <hip/hip_bf16.h>

typedef __hip_bfloat16 bf16;
typedef unsigned long long u64;
typedef __attribute__((ext_vector_type(8))) short short8;   // 8 bf16 = MFMA A/B frag
typedef __attribute__((ext_vector_type(4))) float f32x4;    // MFMA C/D frag

#define B_   2
#define C_   128
#define T_   32
#define N_   512
#define K_   16
#define HID_ 512
#define TN   (T_*N_)          // 16384
#define PTS  (B_*T_*N_)       // 32768

#define MFMA_BF16(a,b,c) __builtin_amdgcn_mfma_f32_16x16x32_bf16((a),(b),(c),0,0,0)

__device__ __forceinline__ float b2f(bf16 v){ return __bfloat162float(v); }
__device__ __forceinline__ bf16  f2b(float v){ return __float2bfloat16(v); }

__device__ __forceinline__ float ldc(const void* p, int i, bool f32) {
  return f32 ? ((const float*)p)[i] : b2f(((const bf16*)p)[i]);
}

// ---------- convert weights + bn; every block locally detects input dtype; blk0 publishes flag ----------
__global__ __launch_bounds__(256) void convw_kernel(
    const void* __restrict__ x,
    const void* wq, const void* wk, const void* wv,
    const void* w1, const void* w2, const void* g, const void* bb,
    const void* m, const void* v,
    bf16* __restrict__ wqb, bf16* __restrict__ wkb, bf16* __restrict__ wvb,
    bf16* __restrict__ w1b, bf16* __restrict__ w2b,
    float* __restrict__ gf, float* __restrict__ bf_, float* __restrict__ mf,
    float* __restrict__ vf, int* __restrict__ flag)
{
  // dtype detect: f32 data viewed as 16-bit halves has ~46% garbage exponents
  __shared__ int cnt;
  if (threadIdx.x == 0) cnt = 0;
  __syncthreads();
  const unsigned short* u = (const unsigned short*)x;
  int w = 0;
#pragma unroll
  for (int j = 0; j < 8; ++j) {
    unsigned short hv = u[threadIdx.x*8 + j];
    int e = (hv >> 7) & 0xFF;
    if (e >= 0x89) w++;
  }
  if (w) atomicAdd(&cnt, w);
  __syncthreads();
  bool f32 = (cnt > 32);
  if (blockIdx.x == 0 && threadIdx.x == 0) *flag = f32 ? 1 : 0;

  int i = blockIdx.x*256 + threadIdx.x;            // grid covers 180736 exactly
  if (i < 16384) { wqb[i] = f2b(ldc(wq, i, f32)); return; } i -= 16384;
  if (i < 16384) { wkb[i] = f2b(ldc(wk, i, f32)); return; } i -= 16384;
  if (i < 16384) { wvb[i] = f2b(ldc(wv, i, f32)); return; } i -= 16384;
  if (i < 65536) { w1b[i] = f2b(ldc(w1, i, f32)); return; } i -= 65536;
  if (i < 65536) { w2b[i] = f2b(ldc(w2, i, f32)); return; } i -= 65536;
  if (i < 128)   { gf[i]  = ldc(g, i, f32); return; }       i -= 128;
  if (i < 128)   { bf_[i] = ldc(bb, i, f32); return; }      i -= 128;
  if (i < 128)   { mf[i]  = ldc(m, i, f32); return; }       i -= 128;
  if (i < 128)   { vf[i]  = ldc(v, i, f32); return; }
}

// ---------- MFMA GEMM helper: D[p][o] += A[p][c]*W[o][c] ----------
__device__ __forceinline__ void proj_gemm(const bf16* __restrict__ W,
                                          bf16 (*ys)[136],
                                          const short8 am[4][4],
                                          int mrow, int quad, int wave)
{
#pragma unroll
  for (int oi = 0; oi < 2; ++oi) {
    int ot = wave*2 + oi;
    f32x4 acc[4];
#pragma unroll
    for (int mt=0;mt<4;++mt) acc[mt] = (f32x4){0.f,0.f,0.f,0.f};
#pragma unroll
    for (int kq=0;kq<4;++kq) {
      short8 bfr = *(const short8*)&W[(ot*16+mrow)*C_ + kq*32 + quad*8];
#pragma unroll
      for (int mt=0;mt<4;++mt) acc[mt] = MFMA_BF16(am[mt][kq], bfr, acc[mt]);
    }
#pragma unroll
    for (int mt=0;mt<4;++mt)
#pragma unroll
      for (int r=0;r<4;++r)
        ys[mt*16 + quad*4 + r][ot*16 + mrow] = f2b(acc[mt][r]);
  }
}

__device__ __forceinline__ void tile_store128(bf16* __restrict__ dst,
                                              const bf16 (*ys)[136], int tid)
{
#pragma unroll
  for (int it=0; it<4; ++it) {
    int flat = (it*256 + tid)*8;
    int p = flat >> 7, c = flat & 127;
    *(short8*)&dst[(size_t)p*C_ + c] = *(const short8*)&ys[p][c];
  }
}

// ---------- QKV projections (MFMA, batched stores) + point-major bf16 copy of x ----------
__global__ __launch_bounds__(256) void proj_kernel(
    const void* __restrict__ x, const int* __restrict__ flag,
    const bf16* __restrict__ wqb, const bf16* __restrict__ wkb, const bf16* __restrict__ wvb,
    bf16* __restrict__ xTb, bf16* QT, bf16* __restrict__ KT, bf16* __restrict__ VT)
{
  __shared__ bf16 xs [64][136];                    // A-tile; reused as Q D-tile
  __shared__ bf16 ysK[64][136];
  __shared__ bf16 ysV[64][136];                    // 52.2 KB total -> 3 blocks/CU
  int tid = threadIdx.x;
  int p0  = blockIdx.x * 64;
  int b   = p0 >> 14; int tn0 = p0 & (TN-1);
  if (*flag) {                                     // f32 inputs
    const float* xbase = (const float*)x + (size_t)b*C_*TN + tn0;
#pragma unroll
    for (int it=0; it<32; ++it) {
      int i = it*256 + tid;
      int c = i >> 6, p = i & 63;                  // coalesced over n
      xs[p][c] = f2b(xbase[(size_t)c*TN + p]);
    }
  } else {                                         // bf16 inputs (bit-exact stage)
    const bf16* xbase = (const bf16*)x + (size_t)b*C_*TN + tn0;
#pragma unroll
    for (int it=0; it<32; ++it) {
      int i = it*256 + tid;
      int c = i >> 6, p = i & 63;
      xs[p][c] = xbase[(size_t)c*TN + p];
    }
  }
  __syncthreads();
  tile_store128(xTb + (size_t)p0*C_, xs, tid);     // point-major bf16 x (reads xs)
  int lane = tid & 63, wave = tid >> 6;
  int mrow = lane & 15, quad = lane >> 4;
  short8 am[4][4];                                 // A-frags (reads xs)
#pragma unroll
  for (int mt=0;mt<4;++mt)
#pragma unroll
    for (int kq=0;kq<4;++kq)
      am[mt][kq] = *(const short8*)&xs[mt*16 + mrow][kq*32 + quad*8];
  __syncthreads();                                 // all xs reads done; xs becomes ysQ
  proj_gemm(wqb, xs,  am, mrow, quad, wave);
  proj_gemm(wkb, ysK, am, mrow, quad, wave);
  proj_gemm(wvb, ysV, am, mrow, quad, wave);
  __syncthreads();
  tile_store128(QT + (size_t)p0*C_, xs,  tid);
  tile_store128(KT + (size_t)p0*C_, ysK, tid);
  tile_store128(VT + (size_t)p0*C_, ysV, tid);
}

// ---------- bitonic helpers ----------
__device__ __forceinline__ u64 shflx64(u64 v, int m) {
  return (u64)__shfl_xor((long long)v, m, 64);
}
template<int W>
__device__ __forceinline__ u64 bitonic64w(u64 key, int lane) {
#pragma unroll
  for (int k = 2; k <= W; k <<= 1) {
#pragma unroll
    for (int j = k >> 1; j >= 1; j >>= 1) {
      u64 p = shflx64(key, j);
      bool keep_min = ((lane & k) == 0) == ((lane & j) == 0);
      key = ((p < key) == keep_min) ? p : key;
    }
  }
  return key;
}
__device__ __forceinline__ unsigned bitonic32u(unsigned key, int lane) {
#pragma unroll
  for (int k = 2; k <= 64; k <<= 1) {
#pragma unroll
    for (int j = k >> 1; j >= 1; j >>= 1) {
      unsigned p = (unsigned)__shfl_xor((int)key, j, 64);
      bool keep_min = ((lane & k) == 0) == ((lane & j) == 0);
      key = ((p < key) == keep_min) ? p : key;
    }
  }
  return key;
}

// ---------- top-K=16 NN v4: float4 candidates, u32 threshold, u64 lex-sort of survivors ----------
// Exactness: d2 in exact numpy order; threshold U_d = 16th-smallest lane-min d
// (pure-d order stat == lex order stat in d-value) -> filter d<=U_d is a
// guaranteed superset of the true top-16; survivors sorted by (d_bits, m) u64
// == top_k order (ties -> lowest pool index).
__global__ __launch_bounds__(512) void knn_kernel(const void* __restrict__ x,
                                                  const int* __restrict__ flag,
                                                  int* __restrict__ idxout)
{
  __shared__ float4 cand4[3*N_];                   // 24 KB, shared by 8 points
  __shared__ u64 surv[8][64];                      // 4 KB
  int tid = threadIdx.x;
  int blk = blockIdx.x;
  int row = blk >> 6;                              // (b,t)
  int b = row >> 5, t = row & 31;
  int ng = blk & 63;
  bool f32 = (*flag != 0);
#pragma unroll
  for (int q = 0; q < 3; ++q) {                    // j=q time slot; 512 cols coalesced
    int tt = t - 1 + q; tt = tt < 0 ? 0 : (tt > T_-1 ? T_-1 : tt);
    size_t base = ((size_t)b*C_*T_ + tt)*(size_t)N_ + tid;   // ch0
    float c0, c1, c2;
    if (f32) {
      const float* xp = (const float*)x;
      c0 = xp[base]; c1 = xp[base + (size_t)T_*N_]; c2 = xp[base + 2*(size_t)T_*N_];
    } else {
      const bf16* xp = (const bf16*)x;
      c0 = b2f(xp[base]); c1 = b2f(xp[base + (size_t)T_*N_]); c2 = b2f(xp[base + 2*(size_t)T_*N_]);
    }
    cand4[q*N_ + tid] = make_float4(c0, c1, c2, 0.f);
  }
  __syncthreads();
  int wave = tid >> 6, lane = tid & 63;
  int n = ng*8 + wave;                             // this wave's point
  float4 a = cand4[N_ + n];                        // self (j=1 slot), broadcast read
  unsigned db[24];                                 // lane owns m = lane + 64j
#pragma unroll
  for (int j = 0; j < 24; ++j) {
    float4 cm = cand4[lane + (j << 6)];            // one ds_read_b128, conflict-free
    float dx = a.x - cm.x;
    float dy = a.y - cm.y;
    float dz = a.z - cm.z;
    // exact numpy order, no fma contraction
    float d2 = __fadd_rn(__fadd_rn(__fmul_rn(dx,dx), __fmul_rn(dy,dy)), __fmul_rn(dz,dz));
    db[j] = __float_as_uint(d2);                   // d2>=0 -> u32 order == f32 order
  }
  // per-lane min d (ascending j + strict < -> lowest m among lane's ties)
  unsigned bd = db[0];
#pragma unroll
  for (int j = 1; j < 24; ++j) bd = (db[j] < bd) ? db[j] : bd;
  // U = 16th smallest lane-min d
  unsigned sd = bitonic32u(bd, lane);
  unsigned U = (unsigned)__shfl((int)sd, 15, 64);
  int c = 0;
#pragma unroll
  for (int j = 0; j < 24; ++j) c += (db[j] <= U) ? 1 : 0;
  int sc = c;                                      // inclusive wave prefix sum
#pragma unroll
  for (int d = 1; d < 64; d <<= 1) {
    int pv = __shfl_up(sc, d, 64);
    if (lane >= d) sc += pv;
  }
  int total = __shfl(sc, 63, 64);
  int ofs = sc - c;
  u64 out16;
  if (total <= 64) {                               // ~always (E[total] ~ 18)
#pragma unroll
    for (int j = 0; j < 24; ++j) {
      if (db[j] <= U) {
        surv[wave][ofs] = ((u64)db[j] << 32) | (unsigned)(lane + (j << 6));
        ++ofs;
      }
    }
    __threadfence_block();
    u64 kk = (lane < total) ? surv[wave][lane] : ~0ull;
    out16 = (total <= 32) ? bitonic64w<32>(kk, lane)
                          : bitonic64w<64>(kk, lane); // lanes 0..15 = exact top-16
  } else {
    u64 key[24];                                   // exact fallback (rare)
#pragma unroll
    for (int j = 0; j < 24; ++j)
      key[j] = ((u64)db[j] << 32) | (unsigned)(lane + (j << 6));
    u64 res = ~0ull;
#pragma unroll 1
    for (int r = 0; r < 16; ++r) {
      u64 m2 = key[0];
#pragma unroll
      for (int j = 1; j < 24; ++j) m2 = (key[j] < m2) ? key[j] : m2;
#pragma unroll
      for (int s = 32; s >= 1; s >>= 1) {
        u64 p = shflx64(m2, s);
        m2 = (p < m2) ? p : m2;
      }
      if (lane == r) res = m2;
      int mwin = (int)(m2 & 0xffffffffu);
      int sel = ((mwin & 63) == lane) ? (mwin >> 6) : -1;
#pragma unroll
      for (int j = 0; j < 24; ++j) if (j == sel) key[j] = ~0ull;
    }
    out16 = res;
  }
  int point = (b*T_ + t)*N_ + n;
  if (lane < K_) idxout[point*K_ + lane] = (int)(out16 & 0xffffffffu);
}

// ---------- attention: 4 points / 512-thread block ----------
__global__ __launch_bounds__(512) void attn_kernel(
    const int* __restrict__ idxin, const bf16* __restrict__ xTb,
    bf16* qhT /* in: QT, out: hT */, const bf16* __restrict__ KT,
    const bf16* __restrict__ VT,
    const float* __restrict__ gf, const float* __restrict__ bf_,
    const float* __restrict__ mf, const float* __restrict__ vf)
{
  __shared__ int   col_lds[4][16];
  __shared__ float qbuf[4][C_];
  __shared__ bf16  kbuf[4][K_][136];
  __shared__ bf16  vbuf[4][K_][136];               // ~38 KB total
  __shared__ float e_lds[4][4][16];
  int tid = threadIdx.x;
  int pt = tid >> 7, o = tid & 127;
  int point = blockIdx.x*4 + pt;
  int b = point >> 14; int tn = point & (TN-1); int t = tn >> 9;
  if (o < K_) {
    int m = idxin[point*K_ + o];
    int j = m >> 9, nn = m & (N_-1);
    int tt = t-1+j; tt = tt<0?0:(tt>T_-1?T_-1:tt);
    col_lds[pt][o] = ((b*T_ + tt)*N_ + nn)*C_;
  }
  int self = point*C_;
  qbuf[pt][o] = b2f(qhT[self + o]);                // QT reads done before first sync
  __syncthreads();
  // gather 64 K/V columns per block as 16B chunks (coalesced 256B per column)
#pragma unroll
  for (int it = 0; it < 2; ++it) {
    int i = it*512 + tid;
    int pp = i >> 8, rem = i & 255, k = rem >> 4, ch = rem & 15;
    int src = col_lds[pp][k] + ch*8;
    *(short8*)&kbuf[pp][k][ch*8] = *(const short8*)&KT[src];
    *(short8*)&vbuf[pp][k][ch*8] = *(const short8*)&VT[src];
  }
  __syncthreads();
  if (tid < 256) {                                 // one thread per (point, head, k)
    int pp = tid >> 6, j = tid & 63, hd = j >> 4, k = j & 15;
    const float* qp = &qbuf[pp][hd*32];
    const bf16*  kp = &kbuf[pp][k][hd*32];
    float e = 0.f;
#pragma unroll
    for (int d=0; d<32; ++d) e = fmaf(qp[d], b2f(kp[d]), e);
    // energy = q.(Kself - Knb)/sqrt(D); self term k-constant -> dropped
    e_lds[pp][hd][k] = -e * 0.17677669529663687f;
  }
  __syncthreads();
  int hd = o >> 5;
  float e[16]; float mx = -3e38f;
#pragma unroll
  for (int k=0;k<K_;++k){ e[k]=e_lds[pt][hd][k]; mx=fmaxf(mx,e[k]); }
  float ssum=0.f;
#pragma unroll
  for (int k=0;k<K_;++k){ e[k]=__expf(e[k]-mx); ssum+=e[k]; }
  float inv = 1.f/ssum;
  float acc = b2f(VT[self + o]);                   // agg = Vself - sum attn*Vnb
#pragma unroll
  for (int k=0;k<K_;++k)
    acc = fmaf(-(e[k]*inv), b2f(vbuf[pt][k][o]), acc);
  float hv = b2f(xTb[self + o]) + acc;
  float sc = gf[o] / sqrtf(vf[o] + 1e-5f);
  qhT[self + o] = f2b((hv - mf[o])*sc + bf_[o]);   // hT role
}

// ---------- fused MLP via MFMA + passthrough ch 0..3 -> all 132 out channels ----------
__global__ __launch_bounds__(256) void mlp_kernel(const bf16* __restrict__ hT,
                                                  const bf16* __restrict__ w1b,
                                                  const bf16* __restrict__ w2b,
                                                  const void* __restrict__ x,
                                                  const int* __restrict__ flag,
                                                  void* out)
{
  __shared__ bf16  hs[64][136];                    // 17.4 KB
  __shared__ bf16  hid[64][520];                   // 66.6 KB
  __shared__ float yf[64][133];                    // 34.0 KB
  int tid = threadIdx.x;
  int p0 = blockIdx.x*64;
  int lane = tid & 63, wave = tid >> 6;
  int mrow = lane & 15, quad = lane >> 4;
  bool f32o = (*flag != 0);
  {                                                // passthrough ch 0..3 for this tile
    int c = tid >> 6, p = tid & 63;
    int pnt = p0 + p;
    int bb = pnt >> 14, tn = pnt & (TN-1);
    size_t si = ((size_t)bb*C_ + c)*TN + tn;
    size_t di = ((size_t)bb*132 + c)*TN + tn;
    if (f32o) ((float*)out)[di] = ((const float*)x)[si];
    else      ((bf16*)out)[di] = ((const bf16*)x)[si];
  }
#pragma unroll
  for (int it=0; it<4; ++it) {
    int flat = (it*256 + tid)*8;
    int p = flat >> 7, c = flat & 127;
    *(short8*)&hs[p][c] = *(const short8*)&hT[(size_t)(p0+p)*C_ + c];
  }
  __syncthreads();
  {
    short8 am[4][4];
#pragma unroll
    for (int mt=0;mt<4;++mt)
#pragma unroll
      for (int kq=0;kq<4;++kq)
        am[mt][kq] = *(const short8*)&hs[mt*16 + mrow][kq*32 + quad*8];
    for (int ot = wave*8; ot < wave*8 + 8; ++ot) {
      f32x4 acc[4];
#pragma unroll
      for (int mt=0;mt<4;++mt) acc[mt] = (f32x4){0.f,0.f,0.f,0.f};
#pragma unroll
      for (int kq=0;kq<4;++kq) {
        short8 bfr = *(const short8*)&w1b[(ot*16+mrow)*C_ + kq*32 + quad*8];
#pragma unroll
        for (int mt=0;mt<4;++mt) acc[mt] = MFMA_BF16(am[mt][kq], bfr, acc[mt]);
      }
#pragma unroll
      for (int mt=0;mt<4;++mt)
#pragma unroll
        for (int r=0;r<4;++r) {
          float z = acc[mt][r];
          hid[mt*16 + quad*4 + r][ot*16 + mrow] = f2b(z > 0.f ? z : 0.2f*z);
        }
    }
  }
  __syncthreads();
  {
    short8 ha[16];
#pragma unroll
    for (int ks=0;ks<16;++ks)
      ha[ks] = *(const short8*)&hid[wave*16 + mrow][ks*32 + quad*8];
#pragma unroll
    for (int otp=0; otp<4; ++otp) {
      f32x4 acc0 = (f32x4){0.f,0.f,0.f,0.f};
      f32x4 acc1 = (f32x4){0.f,0.f,0.f,0.f};
#pragma unroll
      for (int ks=0;ks<16;++ks) {
        short8 b0 = *(const short8*)&w2b[((otp*2  )*16+mrow)*HID_ + ks*32 + quad*8];
        short8 b1 = *(const short8*)&w2b[((otp*2+1)*16+mrow)*HID_ + ks*32 + quad*8];
        acc0 = MFMA_BF16(ha[ks], b0, acc0);
        acc1 = MFMA_BF16(ha[ks], b1, acc1);
      }
#pragma unroll
      for (int r=0;r<4;++r) {
        yf[wave*16 + quad*4 + r][(otp*2  )*16 + mrow] = acc0[r];
        yf[wave*16 + quad*4 + r][(otp*2+1)*16 + mrow] = acc1[r];
      }
    }
  }
  __syncthreads();
  int p = tid & 63;
  int point = p0 + p;
  int b = point >> 14, tn = point & (TN-1);
  size_t obase = (size_t)b*132*TN + tn;
#pragma unroll
  for (int j = 0; j < 32; ++j) {
    int o = (tid >> 6)*32 + j;
    float vv = yf[p][o];
    size_t oi = obase + (size_t)(4+o)*TN;
    if (f32o) ((float*)out)[oi] = vv;
    else      ((bf16*)out)[oi] = f2b(vv);
  }
}

extern "C" void kernel_launch(void* const* d_in, const int* in_sizes, int n_in,
                              void* d_out, int out_size, void* d_ws, size_t ws_size,
                              hipStream_t stream)
{
  (void)in_sizes; (void)n_in; (void)out_size; (void)ws_size;
  const void* x = d_in[0];
  char* ws = (char*)d_ws;
  const size_t MB = (size_t)1<<20;
  bf16*  QT  = (bf16* )(ws + 0*MB);      // 8 MB (becomes hT after attn)
  bf16*  KT  = (bf16* )(ws + 8*MB);      // 8 MB
  bf16*  VT  = (bf16* )(ws + 16*MB);     // 8 MB
  bf16*  xTb = (bf16* )(ws + 24*MB);     // 8 MB
  int*   idxw= (int*  )(ws + 32*MB);     // 2 MB
  bf16*  wqb = (bf16* )(ws + 34*MB);             // 32 KB
  bf16*  wkb = (bf16* )(ws + 34*MB + 0x8000);    // 32 KB
  bf16*  wvb = (bf16* )(ws + 34*MB + 0x10000);   // 32 KB
  bf16*  w1b = (bf16* )(ws + 34*MB + 0x18000);   // 128 KB
  bf16*  w2b = (bf16* )(ws + 34*MB + 0x38000);   // 128 KB
  float* gf  = (float*)(ws + 34*MB + 0x58000);
  float* bf_ = (float*)(ws + 34*MB + 0x58200);
  float* mf  = (float*)(ws + 34*MB + 0x58400);
  float* vf  = (float*)(ws + 34*MB + 0x58600);
  int*  flag = (int*  )(ws + 34*MB + 0x58800);

  convw_kernel<<<dim3(706), dim3(256), 0, stream>>>(
      x, d_in[1], d_in[2], d_in[3], d_in[4], d_in[5],
      d_in[6], d_in[7], d_in[8], d_in[9],
      wqb, wkb, wvb, w1b, w2b, gf, bf_, mf, vf, flag);
  proj_kernel <<<dim3(PTS/64), dim3(256), 0, stream>>>(x, flag, wqb, wkb, wvb, xTb, QT, KT, VT);
  knn_kernel  <<<dim3(PTS/8), dim3(512), 0, stream>>>(x, flag, idxw);
  attn_kernel <<<dim3(PTS/4), dim3(512), 0, stream>>>(idxw, xTb, QT /*->hT*/, KT, VT, gf, bf_, mf, vf);
  mlp_kernel  <<<dim3(PTS/64), dim3(256), 0, stream>>>(QT /*hT*/, w1b, w2b, x, flag, d_out);
}

// Round 9
// 210.878 us; speedup vs baseline: 10.6578x; 1.0158x over previous
//
#include <hip/hip_runtime.h>
#include <hip/hip_bf16.h>

typedef __hip_bfloat16 bf16;
typedef unsigned long long u64;
typedef __attribute__((ext_vector_type(8))) short short8;   // 8 bf16 = MFMA A/B frag
typedef __attribute__((ext_vector_type(4))) float f32x4;    // MFMA C/D frag

#define B_   2
#define C_   128
#define T_   32
#define N_   512
#define K_   16
#define HID_ 512
#define TN   (T_*N_)          // 16384
#define PTS  (B_*T_*N_)       // 32768

#define MFMA_BF16(a,b,c) __builtin_amdgcn_mfma_f32_16x16x32_bf16((a),(b),(c),0,0,0)

__device__ __forceinline__ float b2f(bf16 v){ return __bfloat162float(v); }
__device__ __forceinline__ bf16  f2b(float v){ return __float2bfloat16(v); }

__device__ __forceinline__ float ldc(const void* p, int i, bool f32) {
  return f32 ? ((const float*)p)[i] : b2f(((const bf16*)p)[i]);
}

// ---------- convert weights + bn; every block locally detects input dtype; blk0 publishes flag ----------
__global__ __launch_bounds__(256) void convw_kernel(
    const void* __restrict__ x,
    const void* wq, const void* wk, const void* wv,
    const void* w1, const void* w2, const void* g, const void* bb,
    const void* m, const void* v,
    bf16* __restrict__ wqb, bf16* __restrict__ wkb, bf16* __restrict__ wvb,
    bf16* __restrict__ w1b, bf16* __restrict__ w2b,
    float* __restrict__ gf, float* __restrict__ bf_, float* __restrict__ mf,
    float* __restrict__ vf, int* __restrict__ flag)
{
  // dtype detect: f32 data viewed as 16-bit halves has ~46% garbage exponents
  __shared__ int cnt;
  if (threadIdx.x == 0) cnt = 0;
  __syncthreads();
  const unsigned short* u = (const unsigned short*)x;
  int w = 0;
#pragma unroll
  for (int j = 0; j < 8; ++j) {
    unsigned short hv = u[threadIdx.x*8 + j];
    int e = (hv >> 7) & 0xFF;
    if (e >= 0x89) w++;
  }
  if (w) atomicAdd(&cnt, w);
  __syncthreads();
  bool f32 = (cnt > 32);
  if (blockIdx.x == 0 && threadIdx.x == 0) *flag = f32 ? 1 : 0;

  int i = blockIdx.x*256 + threadIdx.x;            // grid covers 180736 exactly
  if (i < 16384) { wqb[i] = f2b(ldc(wq, i, f32)); return; } i -= 16384;
  if (i < 16384) { wkb[i] = f2b(ldc(wk, i, f32)); return; } i -= 16384;
  if (i < 16384) { wvb[i] = f2b(ldc(wv, i, f32)); return; } i -= 16384;
  if (i < 65536) { w1b[i] = f2b(ldc(w1, i, f32)); return; } i -= 65536;
  if (i < 65536) { w2b[i] = f2b(ldc(w2, i, f32)); return; } i -= 65536;
  if (i < 128)   { gf[i]  = ldc(g, i, f32); return; }       i -= 128;
  if (i < 128)   { bf_[i] = ldc(bb, i, f32); return; }      i -= 128;
  if (i < 128)   { mf[i]  = ldc(m, i, f32); return; }       i -= 128;
  if (i < 128)   { vf[i]  = ldc(v, i, f32); return; }
}

// ---------- MFMA GEMM helper: D[p][o] += A[p][c]*W[o][c] ----------
__device__ __forceinline__ void proj_gemm(const bf16* __restrict__ W,
                                          bf16 (*ys)[136],
                                          const short8 am[4][4],
                                          int mrow, int quad, int wave)
{
#pragma unroll
  for (int oi = 0; oi < 2; ++oi) {
    int ot = wave*2 + oi;
    f32x4 acc[4];
#pragma unroll
    for (int mt=0;mt<4;++mt) acc[mt] = (f32x4){0.f,0.f,0.f,0.f};
#pragma unroll
    for (int kq=0;kq<4;++kq) {
      short8 bfr = *(const short8*)&W[(ot*16+mrow)*C_ + kq*32 + quad*8];
#pragma unroll
      for (int mt=0;mt<4;++mt) acc[mt] = MFMA_BF16(am[mt][kq], bfr, acc[mt]);
    }
#pragma unroll
    for (int mt=0;mt<4;++mt)
#pragma unroll
      for (int r=0;r<4;++r)
        ys[mt*16 + quad*4 + r][ot*16 + mrow] = f2b(acc[mt][r]);
  }
}

__device__ __forceinline__ void tile_store128(bf16* __restrict__ dst,
                                              const bf16 (*ys)[136], int tid)
{
#pragma unroll
  for (int it=0; it<4; ++it) {
    int flat = (it*256 + tid)*8;
    int p = flat >> 7, c = flat & 127;
    *(short8*)&dst[(size_t)p*C_ + c] = *(const short8*)&ys[p][c];
  }
}

// ---------- QKV projections (MFMA, batched stores) + point-major bf16 copy of x ----------
__global__ __launch_bounds__(256) void proj_kernel(
    const void* __restrict__ x, const int* __restrict__ flag,
    const bf16* __restrict__ wqb, const bf16* __restrict__ wkb, const bf16* __restrict__ wvb,
    bf16* __restrict__ xTb, bf16* QT, bf16* __restrict__ KT, bf16* __restrict__ VT)
{
  __shared__ bf16 xs [64][136];                    // A-tile; reused as Q D-tile
  __shared__ bf16 ysK[64][136];
  __shared__ bf16 ysV[64][136];                    // 52.2 KB total -> 3 blocks/CU
  int tid = threadIdx.x;
  int p0  = blockIdx.x * 64;
  int b   = p0 >> 14; int tn0 = p0 & (TN-1);
  if (*flag) {                                     // f32 inputs
    const float* xbase = (const float*)x + (size_t)b*C_*TN + tn0;
#pragma unroll
    for (int it=0; it<32; ++it) {
      int i = it*256 + tid;
      int c = i >> 6, p = i & 63;                  // coalesced over n
      xs[p][c] = f2b(xbase[(size_t)c*TN + p]);
    }
  } else {                                         // bf16 inputs (bit-exact stage)
    const bf16* xbase = (const bf16*)x + (size_t)b*C_*TN + tn0;
#pragma unroll
    for (int it=0; it<32; ++it) {
      int i = it*256 + tid;
      int c = i >> 6, p = i & 63;
      xs[p][c] = xbase[(size_t)c*TN + p];
    }
  }
  __syncthreads();
  tile_store128(xTb + (size_t)p0*C_, xs, tid);     // point-major bf16 x (reads xs)
  int lane = tid & 63, wave = tid >> 6;
  int mrow = lane & 15, quad = lane >> 4;
  short8 am[4][4];                                 // A-frags (reads xs)
#pragma unroll
  for (int mt=0;mt<4;++mt)
#pragma unroll
    for (int kq=0;kq<4;++kq)
      am[mt][kq] = *(const short8*)&xs[mt*16 + mrow][kq*32 + quad*8];
  __syncthreads();                                 // all xs reads done; xs becomes ysQ
  proj_gemm(wqb, xs,  am, mrow, quad, wave);
  proj_gemm(wkb, ysK, am, mrow, quad, wave);
  proj_gemm(wvb, ysV, am, mrow, quad, wave);
  __syncthreads();
  tile_store128(QT + (size_t)p0*C_, xs,  tid);
  tile_store128(KT + (size_t)p0*C_, ysK, tid);
  tile_store128(VT + (size_t)p0*C_, ysV, tid);
}

// ---------- bitonic helpers ----------
__device__ __forceinline__ u64 shflx64(u64 v, int m) {
  return (u64)__shfl_xor((long long)v, m, 64);
}
template<int W>
__device__ __forceinline__ u64 bitonic64w(u64 key, int lane) {
#pragma unroll
  for (int k = 2; k <= W; k <<= 1) {
#pragma unroll
    for (int j = k >> 1; j >= 1; j >>= 1) {
      u64 p = shflx64(key, j);
      bool keep_min = ((lane & k) == 0) == ((lane & j) == 0);
      key = ((p < key) == keep_min) ? p : key;
    }
  }
  return key;
}
__device__ __forceinline__ unsigned bitonic32u(unsigned key, int lane) {
#pragma unroll
  for (int k = 2; k <= 64; k <<= 1) {
#pragma unroll
    for (int j = k >> 1; j >= 1; j >>= 1) {
      unsigned p = (unsigned)__shfl_xor((int)key, j, 64);
      bool keep_min = ((lane & k) == 0) == ((lane & j) == 0);
      key = ((p < key) == keep_min) ? p : key;
    }
  }
  return key;
}

// ---------- top-K=16 NN: float4 candidates, u32 threshold, u64 lex-sort of survivors ----------
__global__ __launch_bounds__(512) void knn_kernel(const void* __restrict__ x,
                                                  const int* __restrict__ flag,
                                                  int* __restrict__ idxout)
{
  __shared__ float4 cand4[3*N_];                   // 24 KB, shared by 8 points
  __shared__ u64 surv[8][64];                      // 4 KB
  int tid = threadIdx.x;
  int blk = blockIdx.x;
  int row = blk >> 6;                              // (b,t)
  int b = row >> 5, t = row & 31;
  int ng = blk & 63;
  bool f32 = (*flag != 0);
#pragma unroll
  for (int q = 0; q < 3; ++q) {                    // j=q time slot; 512 cols coalesced
    int tt = t - 1 + q; tt = tt < 0 ? 0 : (tt > T_-1 ? T_-1 : tt);
    size_t base = ((size_t)b*C_*T_ + tt)*(size_t)N_ + tid;   // ch0
    float c0, c1, c2;
    if (f32) {
      const float* xp = (const float*)x;
      c0 = xp[base]; c1 = xp[base + (size_t)T_*N_]; c2 = xp[base + 2*(size_t)T_*N_];
    } else {
      const bf16* xp = (const bf16*)x;
      c0 = b2f(xp[base]); c1 = b2f(xp[base + (size_t)T_*N_]); c2 = b2f(xp[base + 2*(size_t)T_*N_]);
    }
    cand4[q*N_ + tid] = make_float4(c0, c1, c2, 0.f);
  }
  __syncthreads();
  int wave = tid >> 6, lane = tid & 63;
  int n = ng*8 + wave;                             // this wave's point
  float4 a = cand4[N_ + n];                        // self (j=1 slot), broadcast read
  unsigned db[24];                                 // lane owns m = lane + 64j
#pragma unroll
  for (int j = 0; j < 24; ++j) {
    float4 cm = cand4[lane + (j << 6)];            // one ds_read_b128, conflict-free
    float dx = a.x - cm.x;
    float dy = a.y - cm.y;
    float dz = a.z - cm.z;
    float d2 = __fadd_rn(__fadd_rn(__fmul_rn(dx,dx), __fmul_rn(dy,dy)), __fmul_rn(dz,dz));
    db[j] = __float_as_uint(d2);                   // d2>=0 -> u32 order == f32 order
  }
  unsigned bd = db[0];
#pragma unroll
  for (int j = 1; j < 24; ++j) bd = (db[j] < bd) ? db[j] : bd;
  unsigned sd = bitonic32u(bd, lane);
  unsigned U = (unsigned)__shfl((int)sd, 15, 64);
  int c = 0;
#pragma unroll
  for (int j = 0; j < 24; ++j) c += (db[j] <= U) ? 1 : 0;
  int sc = c;                                      // inclusive wave prefix sum
#pragma unroll
  for (int d = 1; d < 64; d <<= 1) {
    int pv = __shfl_up(sc, d, 64);
    if (lane >= d) sc += pv;
  }
  int total = __shfl(sc, 63, 64);
  int ofs = sc - c;
  u64 out16;
  if (total <= 64) {                               // ~always (E[total] ~ 18)
#pragma unroll
    for (int j = 0; j < 24; ++j) {
      if (db[j] <= U) {
        surv[wave][ofs] = ((u64)db[j] << 32) | (unsigned)(lane + (j << 6));
        ++ofs;
      }
    }
    __threadfence_block();
    u64 kk = (lane < total) ? surv[wave][lane] : ~0ull;
    out16 = (total <= 32) ? bitonic64w<32>(kk, lane)
                          : bitonic64w<64>(kk, lane); // lanes 0..15 = exact top-16
  } else {
    u64 key[24];                                   // exact fallback (rare)
#pragma unroll
    for (int j = 0; j < 24; ++j)
      key[j] = ((u64)db[j] << 32) | (unsigned)(lane + (j << 6));
    u64 res = ~0ull;
#pragma unroll 1
    for (int r = 0; r < 16; ++r) {
      u64 m2 = key[0];
#pragma unroll
      for (int j = 1; j < 24; ++j) m2 = (key[j] < m2) ? key[j] : m2;
#pragma unroll
      for (int s = 32; s >= 1; s >>= 1) {
        u64 p = shflx64(m2, s);
        m2 = (p < m2) ? p : m2;
      }
      if (lane == r) res = m2;
      int mwin = (int)(m2 & 0xffffffffu);
      int sel = ((mwin & 63) == lane) ? (mwin >> 6) : -1;
#pragma unroll
      for (int j = 0; j < 24; ++j) if (j == sel) key[j] = ~0ull;
    }
    out16 = res;
  }
  int point = (b*T_ + t)*N_ + n;
  if (lane < K_) idxout[point*K_ + lane] = (int)(out16 & 0xffffffffu);
}

// ---------- attention: 4 points / 512-thread block ----------
__global__ __launch_bounds__(512) void attn_kernel(
    const int* __restrict__ idxin, const bf16* __restrict__ xTb,
    bf16* qhT /* in: QT, out: hT */, const bf16* __restrict__ KT,
    const bf16* __restrict__ VT,
    const float* __restrict__ gf, const float* __restrict__ bf_,
    const float* __restrict__ mf, const float* __restrict__ vf)
{
  __shared__ int   col_lds[4][16];
  __shared__ float qbuf[4][C_];
  __shared__ bf16  kbuf[4][K_][136];
  __shared__ bf16  vbuf[4][K_][136];               // ~38 KB total
  __shared__ float e_lds[4][4][16];
  int tid = threadIdx.x;
  int pt = tid >> 7, o = tid & 127;
  int point = blockIdx.x*4 + pt;
  int b = point >> 14; int tn = point & (TN-1); int t = tn >> 9;
  if (o < K_) {
    int m = idxin[point*K_ + o];
    int j = m >> 9, nn = m & (N_-1);
    int tt = t-1+j; tt = tt<0?0:(tt>T_-1?T_-1:tt);
    col_lds[pt][o] = ((b*T_ + tt)*N_ + nn)*C_;
  }
  int self = point*C_;
  qbuf[pt][o] = b2f(qhT[self + o]);                // QT reads done before first sync
  __syncthreads();
  // gather 64 K/V columns per block as 16B chunks (coalesced 256B per column)
#pragma unroll
  for (int it = 0; it < 2; ++it) {
    int i = it*512 + tid;
    int pp = i >> 8, rem = i & 255, k = rem >> 4, ch = rem & 15;
    int src = col_lds[pp][k] + ch*8;
    *(short8*)&kbuf[pp][k][ch*8] = *(const short8*)&KT[src];
    *(short8*)&vbuf[pp][k][ch*8] = *(const short8*)&VT[src];
  }
  __syncthreads();
  if (tid < 256) {                                 // one thread per (point, head, k)
    int pp = tid >> 6, j = tid & 63, hd = j >> 4, k = j & 15;
    const float* qp = &qbuf[pp][hd*32];
    const bf16*  kp = &kbuf[pp][k][hd*32];
    float e = 0.f;
#pragma unroll
    for (int d=0; d<32; ++d) e = fmaf(qp[d], b2f(kp[d]), e);
    // energy = q.(Kself - Knb)/sqrt(D); self term k-constant -> dropped
    e_lds[pp][hd][k] = -e * 0.17677669529663687f;
  }
  __syncthreads();
  int hd = o >> 5;
  float e[16]; float mx = -3e38f;
#pragma unroll
  for (int k=0;k<K_;++k){ e[k]=e_lds[pt][hd][k]; mx=fmaxf(mx,e[k]); }
  float ssum=0.f;
#pragma unroll
  for (int k=0;k<K_;++k){ e[k]=__expf(e[k]-mx); ssum+=e[k]; }
  float inv = 1.f/ssum;
  float acc = b2f(VT[self + o]);                   // agg = Vself - sum attn*Vnb
#pragma unroll
  for (int k=0;k<K_;++k)
    acc = fmaf(-(e[k]*inv), b2f(vbuf[pt][k][o]), acc);
  float hv = b2f(xTb[self + o]) + acc;
  float sc = gf[o] / sqrtf(vf[o] + 1e-5f);
  qhT[self + o] = f2b((hv - mf[o])*sc + bf_[o]);   // hT role
}

// ---------- fused MLP v2: 32-pt tiles, half-k hid in 16.5KB LDS, direct stores ----------
__global__ __launch_bounds__(256) void mlp_kernel(const bf16* __restrict__ hT,
                                                  const bf16* __restrict__ w1b,
                                                  const bf16* __restrict__ w2b,
                                                  const void* __restrict__ x,
                                                  const int* __restrict__ flag,
                                                  void* out)
{
  __shared__ bf16 hidh[32][264];                   // 16.5 KB (row 528B, 16B-aligned)
  int tid = threadIdx.x;
  int p0 = blockIdx.x*32;
  int lane = tid & 63, wave = tid >> 6;
  int mrow = lane & 15, quad = lane >> 4;
  bool f32o = (*flag != 0);
  int bb = p0 >> 14;                               // block never straddles b
  int tn0 = p0 & (TN-1);
  if (tid < 128) {                                 // passthrough ch 0..3 (bit copy)
    int c = tid >> 5, p = tid & 31;
    size_t si = ((size_t)bb*C_ + c)*TN + tn0 + p;
    size_t di = ((size_t)bb*132 + c)*TN + tn0 + p;
    if (f32o) ((float*)out)[di] = ((const float*)x)[si];
    else      ((bf16*)out)[di]  = ((const bf16*)x)[si];
  }
  f32x4 acc2[2][2];                                // [otile][mtile], persists both halves
#pragma unroll
  for (int oi=0;oi<2;++oi)
#pragma unroll
    for (int mt=0;mt<2;++mt) acc2[oi][mt] = (f32x4){0.f,0.f,0.f,0.f};

#pragma unroll
  for (int half = 0; half < 2; ++half) {
    if (half) __syncthreads();                     // prev stage2 reads done
    // ---- stage 1: hid cols [half*256, half*256+256) = leaky_relu(H x W1^T) ----
    short8 am[2][4];                               // A-frags straight from global hT
#pragma unroll
    for (int mt=0;mt<2;++mt)
#pragma unroll
      for (int kq=0;kq<4;++kq)
        am[mt][kq] = *(const short8*)&hT[(size_t)(p0 + mt*16 + mrow)*C_ + kq*32 + quad*8];
#pragma unroll
    for (int oi = 0; oi < 4; ++oi) {               // wave owns 4 of this half's 16 otiles
      int ot_g = half*16 + wave*4 + oi;
      int otl  = wave*4 + oi;
      f32x4 acc[2];
#pragma unroll
      for (int mt=0;mt<2;++mt) acc[mt] = (f32x4){0.f,0.f,0.f,0.f};
#pragma unroll
      for (int kq=0;kq<4;++kq) {
        short8 bfr = *(const short8*)&w1b[(ot_g*16+mrow)*C_ + kq*32 + quad*8];
#pragma unroll
        for (int mt=0;mt<2;++mt) acc[mt] = MFMA_BF16(am[mt][kq], bfr, acc[mt]);
      }
#pragma unroll
      for (int mt=0;mt<2;++mt)
#pragma unroll
        for (int r=0;r<4;++r) {
          float z = acc[mt][r];
          hidh[mt*16 + quad*4 + r][otl*16 + mrow] = f2b(z > 0.f ? z : 0.2f*z);
        }
    }
    __syncthreads();
    // ---- stage 2 partial: acc += hid_half x W2_half^T ----
#pragma unroll
    for (int kc = 0; kc < 4; ++kc) {               // 4 chunks of 2 k-slices
      short8 ha[2][2];
#pragma unroll
      for (int mt=0;mt<2;++mt)
#pragma unroll
        for (int kk=0;kk<2;++kk)
          ha[mt][kk] = *(const short8*)&hidh[mt*16 + mrow][(kc*2+kk)*32 + quad*8];
#pragma unroll
      for (int oi=0;oi<2;++oi) {
        int ot2 = wave*2 + oi;                     // wave owns 2 of 8 output otiles
#pragma unroll
        for (int kk=0;kk<2;++kk) {
          int ks_g = half*8 + kc*2 + kk;
          short8 bfr = *(const short8*)&w2b[(ot2*16+mrow)*HID_ + ks_g*32 + quad*8];
#pragma unroll
          for (int mt=0;mt<2;++mt)
            acc2[oi][mt] = MFMA_BF16(ha[mt][kk], bfr, acc2[oi][mt]);
        }
      }
    }
  }
  // ---- direct global stores: lane owns 4 consecutive points per (ot,mt) ----
  size_t obase = (size_t)bb*132*TN;
#pragma unroll
  for (int oi=0;oi<2;++oi) {
    int ch = (wave*2+oi)*16 + mrow;
#pragma unroll
    for (int mt=0;mt<2;++mt) {
      int tn = tn0 + mt*16 + quad*4;
      size_t oidx = obase + (size_t)(4+ch)*TN + tn;
      if (f32o) {
        *(f32x4*)&((float*)out)[oidx] = acc2[oi][mt];
      } else {
        bf16 tmp[4];
#pragma unroll
        for (int r=0;r<4;++r) tmp[r] = f2b(acc2[oi][mt][r]);
        *(u64*)&((bf16*)out)[oidx] = *(u64*)tmp;
      }
    }
  }
}

extern "C" void kernel_launch(void* const* d_in, const int* in_sizes, int n_in,
                              void* d_out, int out_size, void* d_ws, size_t ws_size,
                              hipStream_t stream)
{
  (void)in_sizes; (void)n_in; (void)out_size; (void)ws_size;
  const void* x = d_in[0];
  char* ws = (char*)d_ws;
  const size_t MB = (size_t)1<<20;
  bf16*  QT  = (bf16* )(ws + 0*MB);      // 8 MB (becomes hT after attn)
  bf16*  KT  = (bf16* )(ws + 8*MB);      // 8 MB
  bf16*  VT  = (bf16* )(ws + 16*MB);     // 8 MB
  bf16*  xTb = (bf16* )(ws + 24*MB);     // 8 MB
  int*   idxw= (int*  )(ws + 32*MB);     // 2 MB
  bf16*  wqb = (bf16* )(ws + 34*MB);             // 32 KB
  bf16*  wkb = (bf16* )(ws + 34*MB + 0x8000);    // 32 KB
  bf16*  wvb = (bf16* )(ws + 34*MB + 0x10000);   // 32 KB
  bf16*  w1b = (bf16* )(ws + 34*MB + 0x18000);   // 128 KB
  bf16*  w2b = (bf16* )(ws + 34*MB + 0x38000);   // 128 KB
  float* gf  = (float*)(ws + 34*MB + 0x58000);
  float* bf_ = (float*)(ws + 34*MB + 0x58200);
  float* mf  = (float*)(ws + 34*MB + 0x58400);
  float* vf  = (float*)(ws + 34*MB + 0x58600);
  int*  flag = (int*  )(ws + 34*MB + 0x58800);

  convw_kernel<<<dim3(706), dim3(256), 0, stream>>>(
      x, d_in[1], d_in[2], d_in[3], d_in[4], d_in[5],
      d_in[6], d_in[7], d_in[8], d_in[9],
      wqb, wkb, wvb, w1b, w2b, gf, bf_, mf, vf, flag);
  proj_kernel <<<dim3(PTS/64), dim3(256), 0, stream>>>(x, flag, wqb, wkb, wvb, xTb, QT, KT, VT);
  knn_kernel  <<<dim3(PTS/8), dim3(512), 0, stream>>>(x, flag, idxw);
  attn_kernel <<<dim3(PTS/4), dim3(512), 0, stream>>>(idxw, xTb, QT /*->hT*/, KT, VT, gf, bf_, mf, vf);
  mlp_kernel  <<<dim3(PTS/32), dim3(256), 0, stream>>>(QT /*hT*/, w1b, w2b, x, flag, d_out);
}